// Round 8
// baseline (235.886 us; speedup 1.0000x reference)
//
#include <hip/hip_runtime.h>
#include <math.h>

// Problem constants (fixed by setup_inputs)
#define BB 256      // batch
#define TT 256      // time steps
#define NQ 1000     // num_q
#define DK 128
#define DV 128
#define CC 32

typedef short s16x8 __attribute__((ext_vector_type(8)));   // 8 bf16 bit-patterns
typedef float f32x4 __attribute__((ext_vector_type(4)));
typedef float f32x2 __attribute__((ext_vector_type(2)));

__device__ __forceinline__ float fast_sigmoid(float x) {
    x = fminf(fmaxf(x, -30.f), 30.f);
    return 1.f / (1.f + __expf(-x));
}
__device__ __forceinline__ float fast_tanh(float x) {
    x = fminf(fmaxf(x, -15.f), 15.f);
    float t = __expf(2.f * x);
    return (t - 1.f) / (t + 1.f);
}
__device__ __forceinline__ unsigned short f2bf(float f) {   // RNE fp32->bf16
    unsigned u = __float_as_uint(f);
    u += 0x7fffu + ((u >> 16) & 1u);
    return (unsigned short)(u >> 16);
}
__device__ __forceinline__ float bf2f(unsigned short h) {
    return __uint_as_float((unsigned)h << 16);
}
__device__ __forceinline__ unsigned u4get(uint4 v, int i) { // i constant after unroll
    return i == 0 ? v.x : i == 1 ? v.y : i == 2 ? v.z : v.w;
}
__device__ __forceinline__ f32x2 mk2(float x, float y) { f32x2 r; r.x = x; r.y = y; return r; }
__device__ __forceinline__ f32x2 fma2(f32x2 a, f32x2 b, f32x2 c) {
    return __builtin_elementwise_fma(a, b, c);
}

// ---------------------------------------------------------------------------
// conv_kernel: build bf16 TRANSPOSED weights in ws (B-operand layout Wt[n][k])
// ---------------------------------------------------------------------------
__global__ __launch_bounds__(256) void conv_kernel(
    const float* __restrict__ eW, const float* __restrict__ aW,
    const float* __restrict__ fW, const float* __restrict__ Mk,
    unsigned short* __restrict__ eWt, unsigned short* __restrict__ aWt,
    unsigned short* __restrict__ fWat, unsigned short* __restrict__ fWbt,
    unsigned short* __restrict__ Mkt)
{
    int idx = blockIdx.x * 256 + threadIdx.x;
    if (idx < 16384) {
        int n = idx >> 7, k = idx & 127;
        eWt[idx] = f2bf(eW[k * 128 + n]);
    } else if (idx < 32768) {
        int i = idx - 16384; int n = i >> 7, k = i & 127;
        aWt[i] = f2bf(aW[k * 128 + n]);
    } else if (idx < 49152) {
        int i = idx - 32768; int n = i >> 7, k = i & 127;
        fWat[i] = f2bf(fW[k * 128 + n]);
    } else if (idx < 65536) {
        int i = idx - 49152; int n = i >> 7, k = i & 127;
        fWbt[i] = f2bf(fW[(128 + k) * 128 + n]);
    } else if (idx < 69632) {
        int i = idx - 65536; int n = i >> 7, k = i & 127;   // n=c 0..31
        Mkt[i] = f2bf(Mk[k * 32 + n]);
    }
}

// ---------------------------------------------------------------------------
// MFMA helper: wave computes 16 rows x (NT*16) cols, K=128.
// ---------------------------------------------------------------------------
template <int NT, class F>
__device__ __forceinline__ void mfma_phase(const unsigned short* Wlds,
                                           const s16x8 (&aF)[4], int lane, F emit)
{
    const int quad = lane >> 4, nrow = lane & 15;
#pragma unroll
    for (int nt = 0; nt < NT; ++nt) {
        f32x4 acc = {0.f, 0.f, 0.f, 0.f};
#pragma unroll
        for (int kb = 0; kb < 4; ++kb) {
            s16x8 bf = *(const s16x8*)&Wlds[(nt * 16 + nrow) * 136 + kb * 32 + quad * 8];
            acc = __builtin_amdgcn_mfma_f32_16x16x32_bf16(aF[kb], bf, acc, 0, 0, 0);
        }
        int col = nt * 16 + nrow;
        emit(quad * 4 + 0, col, acc[0]);
        emit(quad * 4 + 1, col, acc[1]);
        emit(quad * 4 + 2, col, acc[2]);
        emit(quad * 4 + 3, col, acc[3]);
    }
}

// ---------------------------------------------------------------------------
// pre_kernel (MFMA, unchanged from R7)
// ---------------------------------------------------------------------------
__global__ __launch_bounds__(256) void pre_kernel(
    const int* __restrict__ skills, const int* __restrict__ responses,
    const float* __restrict__ k_emb, const float* __restrict__ v_emb,
    const float* __restrict__ fb, const float* __restrict__ eb,
    const float* __restrict__ ab,
    const unsigned short* __restrict__ Mkt, const unsigned short* __restrict__ fWbt,
    const unsigned short* __restrict__ eWt, const unsigned short* __restrict__ aWt,
    float* __restrict__ Wo, unsigned* __restrict__ EA,
    unsigned short* __restrict__ Ko, float* __restrict__ outTrue,
    int t0, int Tc)
{
    const int tid = threadIdx.x;
    const int lane = tid & 63;
    const int m_base = (tid >> 6) * 16;
    const int mrow = lane & 15, quad = lane >> 4;
    const size_t base = (size_t)blockIdx.x * 64;

    __shared__ __align__(16) unsigned short Albs[64 * 136];
    __shared__ __align__(16) unsigned short Wlds[128 * 136];
    __shared__ float lg[64 * 33];
    __shared__ int sIdx[64], qIdx[64];

    if (tid < 64) {
        int flat = (int)base + tid;
        int b = flat / Tc, tcc = flat % Tc;
        int t = t0 + tcc;
        int gi = b * TT + t;
        int s = skills[gi];
        int r = responses[gi];
        sIdx[tid] = s;
        qIdx[tid] = s + NQ * ((r > -1) ? r : 0);
        if (t >= 1) outTrue[b * (TT - 1) + (t - 1)] = (float)r;
    }
    __syncthreads();

    {
        int row = tid >> 2, c0 = (tid & 3) * 32;
        int s = sIdx[row];
        const float* src = k_emb + (size_t)s * DK + c0;
#pragma unroll
        for (int j = 0; j < 8; ++j) {
            float4 v = *(const float4*)(src + j * 4);
            unsigned short* dp = &Albs[row * 136 + c0 + j * 4];
            dp[0] = f2bf(v.x); dp[1] = f2bf(v.y); dp[2] = f2bf(v.z); dp[3] = f2bf(v.w);
        }
        int n = tid >> 3, k0 = (tid & 7) * 16;
        *(s16x8*)&Wlds[n * 136 + k0]     = *(const s16x8*)&Mkt[n * 128 + k0];
        *(s16x8*)&Wlds[n * 136 + k0 + 8] = *(const s16x8*)&Mkt[n * 128 + k0 + 8];
    }
    __syncthreads();

    s16x8 aF[4];
#pragma unroll
    for (int kb = 0; kb < 4; ++kb)
        aF[kb] = *(const s16x8*)&Albs[(m_base + mrow) * 136 + kb * 32 + quad * 8];
    mfma_phase<2>(Wlds, aF, lane, [&](int ml, int col, float x) {
        lg[(m_base + ml) * 33 + col] = x;
    });
    __syncthreads();

    {
        int n = tid >> 1, k0 = (tid & 1) * 64;
#pragma unroll
        for (int j = 0; j < 8; ++j)
            *(s16x8*)&Wlds[n * 136 + k0 + j * 8] = *(const s16x8*)&fWbt[n * 128 + k0 + j * 8];
    }
    if (tid < 64) {
        float m = -1e30f;
#pragma unroll
        for (int c = 0; c < CC; ++c) m = fmaxf(m, lg[tid * 33 + c]);
        float ex[CC]; float sum = 0.f;
#pragma unroll
        for (int c = 0; c < CC; ++c) { ex[c] = __expf(lg[tid * 33 + c] - m); sum += ex[c]; }
        float inv = 1.f / sum;
        float* wp = Wo + (base + tid) * CC;
#pragma unroll
        for (int c = 0; c < CC; c += 4)
            *(float4*)(wp + c) = make_float4(ex[c] * inv, ex[c + 1] * inv,
                                             ex[c + 2] * inv, ex[c + 3] * inv);
    }
    __syncthreads();

    mfma_phase<8>(Wlds, aF, lane, [&](int ml, int col, float x) {
        size_t r = base + m_base + ml;
        Ko[r * 128 + col] = f2bf(x + fb[col]);
    });
    __syncthreads();

    {
        int row = tid >> 2, c0 = (tid & 3) * 32;
        int q = qIdx[row];
        const float* src = v_emb + (size_t)q * DV + c0;
#pragma unroll
        for (int j = 0; j < 8; ++j) {
            float4 v = *(const float4*)(src + j * 4);
            unsigned short* dp = &Albs[row * 136 + c0 + j * 4];
            dp[0] = f2bf(v.x); dp[1] = f2bf(v.y); dp[2] = f2bf(v.z); dp[3] = f2bf(v.w);
        }
        int n = tid >> 1, k0 = (tid & 1) * 64;
#pragma unroll
        for (int j = 0; j < 8; ++j)
            *(s16x8*)&Wlds[n * 136 + k0 + j * 8] = *(const s16x8*)&eWt[n * 128 + k0 + j * 8];
    }
    __syncthreads();

#pragma unroll
    for (int kb = 0; kb < 4; ++kb)
        aF[kb] = *(const s16x8*)&Albs[(m_base + mrow) * 136 + kb * 32 + quad * 8];
    // phase 6: et -> Albs (vt frags already in regs)
    mfma_phase<8>(Wlds, aF, lane, [&](int ml, int col, float x) {
        Albs[(m_base + ml) * 136 + col] = f2bf(fast_sigmoid(x + eb[col]));
    });
    __syncthreads();

    {
        int n = tid >> 1, k0 = (tid & 1) * 64;
#pragma unroll
        for (int j = 0; j < 8; ++j)
            *(s16x8*)&Wlds[n * 136 + k0 + j * 8] = *(const s16x8*)&aWt[n * 128 + k0 + j * 8];
    }
    __syncthreads();

    // phase 8: at + pack(et,at) -> one 4B store
    mfma_phase<8>(Wlds, aF, lane, [&](int ml, int col, float x) {
        size_t r = base + m_base + ml;
        int bb = (int)(r / (size_t)Tc);
        int t  = (int)(r - (size_t)bb * Tc);
        size_t o4 = (((size_t)bb * (Tc >> 5) + (t >> 5)) * 8 + ((t >> 2) & 7)) * 128 + col;
        unsigned lo = Albs[(m_base + ml) * 136 + col];
        unsigned hi = (unsigned)f2bf(fast_tanh(x + ab[col])) << 16;
        EA[o4 * 4 + (t & 3)] = hi | lo;
    });
}

// ---------------------------------------------------------------------------
// fused_kernel v2 (seq + post), R8 changes:
//  * w rows REGISTER-PREFETCHED one step ahead (wA/wB ping-pong arrays,
//    constant indices only — R6-proven SROA-safe; peeled loop) so the
//    ~120 cyc ds_read latency is covered by the previous step's ~115 cyc
//    of packed-FMA compute instead of sitting on the Mv dependence chain.
//  * rtl/fWl row stride 136 -> 140 shorts (70 dw = 6 mod 32): consumer
//    MFMA-fragment b128 reads drop from ~8-way to ~<=4-way start-bank
//    aliasing, freeing LDS-pipe cycles for the producers.
// ---------------------------------------------------------------------------

#define CH 32
#define WROW 36     // Wl row stride (floats)
#define RSTR 140    // rtl/fWl row stride (shorts)

#define LOAD_W(gg) do {                                                       \
    const float* ws = Wb + (size_t)(gg) * CH * 32;                            \
    wr0 = *(const float4*)(ws + tid * 8);                                     \
    wr1 = *(const float4*)(ws + tid * 8 + 4);                                 \
} while (0)

#define PUB_W(gg) do {                                                        \
    float* wd = &Wl[(gg) & 1][lr * WROW + lq * 8];                            \
    *(float4*)wd = wr0; *(float4*)(wd + 4) = wr1;                             \
} while (0)

#define LOAD_EA(ER, gg) do {                                                  \
    const uint4* src = EA4 + ((size_t)(bq + (gg))) * 1024 + tid;              \
    _Pragma("unroll")                                                         \
    for (int j = 0; j < 8; ++j) ER[j] = src[j * 128];                         \
} while (0)

// prefetch w row `rowidx` of current chunk into register array WREG[8]
#define W_PREF(WREG, rowidx) do {                                             \
    const float* _wr = wlc + (rowidx) * WROW;                                 \
    _Pragma("unroll")                                                         \
    for (int q = 0; q < 8; ++q) WREG[q] = *(const float4*)(_wr + q * 4);      \
} while (0)

// one chain step from register-resident w
#define SEQ_STEP(WREG, ER, tl) do {                                           \
    f32x2 w2[16];                                                             \
    _Pragma("unroll")                                                         \
    for (int q = 0; q < 8; ++q) {                                             \
        w2[2*q]   = mk2(WREG[q].x, WREG[q].y);                                \
        w2[2*q+1] = mk2(WREG[q].z, WREG[q].w);                                \
    }                                                                         \
    unsigned ea = u4get(ER[(tl) >> 2], (tl) & 3);                             \
    float e = __uint_as_float(ea << 16);                                      \
    float a = __uint_as_float(ea & 0xffff0000u);                              \
    f32x2 ne2 = mk2(-e, -e);                                                  \
    f32x2 a2  = mk2(a, a);                                                    \
    f32x2 r0 = mk2(0.f, 0.f), r1 = r0, r2 = r0, r3 = r0;                      \
    _Pragma("unroll")                                                         \
    for (int q = 0; q < 4; ++q) {                                             \
        r0 = fma2(w2[4*q+0], Mv2[4*q+0], r0);                                 \
        r1 = fma2(w2[4*q+1], Mv2[4*q+1], r1);                                 \
        r2 = fma2(w2[4*q+2], Mv2[4*q+2], r2);                                 \
        r3 = fma2(w2[4*q+3], Mv2[4*q+3], r3);                                 \
    }                                                                         \
    f32x2 rs = (r0 + r1) + (r2 + r3);                                         \
    slp[(tl) * RSTR + tid] = f2bf(rs.x + rs.y);                               \
    _Pragma("unroll")                                                         \
    for (int i = 0; i < 16; ++i)                                              \
        Mv2[i] = fma2(w2[i], fma2(ne2, Mv2[i], a2), Mv2[i]);                  \
} while (0)

#define SEQ_CHUNK(ER, gg, SL) do {                                            \
    const float* wlc = Wl[(gg) & 1];                                          \
    unsigned short* slp = SL;                                                 \
    W_PREF(wA, 0);                                                            \
    _Pragma("unroll")                                                         \
    for (int jp = 0; jp < 15; ++jp) {                                         \
        W_PREF(wB, 2 * jp + 1); SEQ_STEP(wA, ER, 2 * jp);                     \
        W_PREF(wA, 2 * jp + 2); SEQ_STEP(wB, ER, 2 * jp + 1);                 \
    }                                                                         \
    W_PREF(wB, 31); SEQ_STEP(wA, ER, 30);                                     \
    SEQ_STEP(wB, ER, 31);                                                     \
} while (0)

__device__ __forceinline__ void consume_chunk(
    int gc, const unsigned short* sl, const unsigned short* fWl,
    int b, int Tc, int t0,
    const unsigned short* __restrict__ Ko, const float* __restrict__ pW,
    float pbv, float* __restrict__ pred, int tid)
{
    const int lane = tid & 63;
    const int cw = (tid >> 6) & 1;          // consumer wave 0/1 -> rows cw*16..+15
    const int mrow = lane & 15, quad = lane >> 4;
    s16x8 aF[4];
#pragma unroll
    for (int kb = 0; kb < 4; ++kb)
        aF[kb] = *(const s16x8*)&sl[(cw * 16 + mrow) * RSTR + kb * 32 + quad * 8];
    float p0 = 0.f, p1 = 0.f, p2 = 0.f, p3 = 0.f;
    size_t rbase = (size_t)b * Tc + gc * CH + cw * 16 + quad * 4;
#pragma unroll
    for (int nt = 0; nt < 8; ++nt) {
        f32x4 acc = {0.f, 0.f, 0.f, 0.f};
#pragma unroll
        for (int kb = 0; kb < 4; ++kb) {
            s16x8 bf = *(const s16x8*)&fWl[(nt * 16 + mrow) * RSTR + kb * 32 + quad * 8];
            acc = __builtin_amdgcn_mfma_f32_16x16x32_bf16(aF[kb], bf, acc, 0, 0, 0);
        }
        int col = nt * 16 + mrow;
        float pw = pW[col];
        p0 = fmaf(fast_tanh(acc[0] + bf2f(Ko[(rbase + 0) * 128 + col])), pw, p0);
        p1 = fmaf(fast_tanh(acc[1] + bf2f(Ko[(rbase + 1) * 128 + col])), pw, p1);
        p2 = fmaf(fast_tanh(acc[2] + bf2f(Ko[(rbase + 2) * 128 + col])), pw, p2);
        p3 = fmaf(fast_tanh(acc[3] + bf2f(Ko[(rbase + 3) * 128 + col])), pw, p3);
    }
#pragma unroll
    for (int off = 1; off < 16; off <<= 1) {
        p0 += __shfl_xor(p0, off, 64); p1 += __shfl_xor(p1, off, 64);
        p2 += __shfl_xor(p2, off, 64); p3 += __shfl_xor(p3, off, 64);
    }
    if (mrow == 0) {
        int tb = t0 + gc * CH + cw * 16 + quad * 4;
        float ps[4] = {p0, p1, p2, p3};
#pragma unroll
        for (int reg = 0; reg < 4; ++reg) {
            int t = tb + reg;
            if (t < TT - 1) pred[b * (TT - 1) + t] = fast_sigmoid(ps[reg] + pbv);
        }
    }
}

__global__ __launch_bounds__(256, 1) void fused_kernel(
    const float* __restrict__ W, const unsigned* __restrict__ EA,
    const float* __restrict__ Mv0, const unsigned short* __restrict__ Ko,
    const unsigned short* __restrict__ fWat, const float* __restrict__ pW,
    const float* __restrict__ pb,
    float* __restrict__ pred, float* __restrict__ MvWS,
    int t0, int Tc, int doInit, int doSave)
{
    const int b = blockIdx.x;
    const int tid = threadIdx.x;
    const int nch = Tc / CH;

    __shared__ __align__(16) float Wl[2][CH * WROW];            //  9.2 KB
    __shared__ __align__(16) unsigned short rtl[2][CH * RSTR];  // 17.9 KB
    __shared__ __align__(16) unsigned short fWl[128 * RSTR];    // 35.8 KB

    // stage fWat -> fWl (all 256 threads)
    {
        int n = tid >> 1, k0 = (tid & 1) * 64;
#pragma unroll
        for (int j = 0; j < 8; ++j)
            *(s16x8*)&fWl[n * RSTR + k0 + j * 8] = *(const s16x8*)&fWat[n * 128 + k0 + j * 8];
    }

    const int lr = tid >> 2, lq = tid & 3;
    const float* __restrict__ Wb = W + (size_t)b * Tc * 32;
    const uint4* __restrict__ EA4 = (const uint4*)EA;
    const int bq = b * nch;
    f32x2 Mv2[16];
    float4 wr0, wr1;
    float4 wA[8], wB[8];
    uint4 erA[8], erB[8];
    float pbv = 0.f;

    if (tid < 128) {
        if (doInit) {
#pragma unroll
            for (int i = 0; i < 16; ++i)
                Mv2[i] = mk2(Mv0[(2 * i) * 128 + tid], Mv0[(2 * i + 1) * 128 + tid]);
        } else {
#pragma unroll
            for (int i = 0; i < 16; ++i)
                Mv2[i] = mk2(MvWS[(size_t)b * 4096 + (2 * i) * 128 + tid],
                             MvWS[(size_t)b * 4096 + (2 * i + 1) * 128 + tid]);
        }
        LOAD_W(0); PUB_W(0);
        LOAD_EA(erA, 0);
        if (nch > 1) LOAD_W(1);
    } else {
        pbv = pb[0];
    }
    __syncthreads();

    for (int g = 0; g < nch; g += 2) {
        // ---- even chunk g: produce -> slot0; consume chunk g-1 (slot1) ----
        if (tid < 128) {
            if (g + 1 < nch) PUB_W(g + 1);
            if (g + 2 < nch) LOAD_W(g + 2);
            if (g + 1 < nch) LOAD_EA(erB, g + 1);
            SEQ_CHUNK(erA, g, rtl[0]);
        } else if (g >= 1) {
            consume_chunk(g - 1, rtl[1], fWl, b, Tc, t0, Ko, pW, pbv, pred, tid);
        }
        __syncthreads();

        // ---- odd chunk g+1: produce -> slot1; consume chunk g (slot0) ----
        if (tid < 128) {
            if (g + 1 < nch) {
                if (g + 2 < nch) PUB_W(g + 2);
                if (g + 3 < nch) LOAD_W(g + 3);
                if (g + 2 < nch) LOAD_EA(erA, g + 2);
                SEQ_CHUNK(erB, g + 1, rtl[1]);
            }
        } else {
            consume_chunk(g, rtl[0], fWl, b, Tc, t0, Ko, pW, pbv, pred, tid);
        }
        __syncthreads();
    }
    // epilogue: for even nch the last (odd) chunk is still unconsumed
    if (!(nch & 1) && tid >= 128) {
        consume_chunk(nch - 1, rtl[1], fWl, b, Tc, t0, Ko, pW, pbv, pred, tid);
    }

    if (doSave && tid < 128) {
#pragma unroll
        for (int i = 0; i < 16; ++i) {
            MvWS[(size_t)b * 4096 + (2 * i) * 128 + tid]     = Mv2[i].x;
            MvWS[(size_t)b * 4096 + (2 * i + 1) * 128 + tid] = Mv2[i].y;
        }
    }
}

// ---------------------------------------------------------------------------

extern "C" void kernel_launch(void* const* d_in, const int* in_sizes, int n_in,
                              void* d_out, int out_size, void* d_ws, size_t ws_size,
                              hipStream_t stream) {
    const int*   skills    = (const int*)d_in[0];
    const int*   responses = (const int*)d_in[1];
    const float* k_emb     = (const float*)d_in[2];
    const float* v_emb     = (const float*)d_in[3];
    const float* Mk        = (const float*)d_in[4];
    const float* Mv0       = (const float*)d_in[5];
    const float* f_W       = (const float*)d_in[6];
    const float* f_b       = (const float*)d_in[7];
    const float* p_W       = (const float*)d_in[8];
    const float* p_b       = (const float*)d_in[9];
    const float* e_W       = (const float*)d_in[10];
    const float* e_b       = (const float*)d_in[11];
    const float* a_W       = (const float*)d_in[12];
    const float* a_b       = (const float*)d_in[13];

    float* pred    = (float*)d_out;                 // [256][255]
    float* outTrue = pred + BB * (TT - 1);          // [256][255]

    // scratch per row: Wo 128 B + EA 512 B + Ko 256 B = 896 B
    int Tc = TT;
    for (;;) {
        size_t need = (size_t)BB * Tc * 896 + 69632 * 2;
        if (Tc < TT) need += (size_t)BB * 4096 * 4;
        if (need <= ws_size || Tc <= 32) break;
        Tc >>= 1;
    }

    char* p = (char*)d_ws;
    float* Wo = (float*)p;                     p += (size_t)BB * Tc * 32 * 4;
    unsigned* EA = (unsigned*)p;               p += (size_t)BB * Tc * 128 * 4;
    unsigned short* Ko = (unsigned short*)p;   p += (size_t)BB * Tc * 128 * 2;
    unsigned short* eWt = (unsigned short*)p;  p += 16384 * 2;
    unsigned short* aWt = (unsigned short*)p;  p += 16384 * 2;
    unsigned short* fWat = (unsigned short*)p; p += 16384 * 2;
    unsigned short* fWbt = (unsigned short*)p; p += 16384 * 2;
    unsigned short* Mkt = (unsigned short*)p;  p += 4096 * 2;
    float* MvWS = (float*)p;

    conv_kernel<<<272, 256, 0, stream>>>(e_W, a_W, f_W, Mk,
                                         eWt, aWt, fWat, fWbt, Mkt);

    for (int t0 = 0; t0 < TT; t0 += Tc) {
        pre_kernel<<<(BB * Tc) / 64, 256, 0, stream>>>(
            skills, responses, k_emb, v_emb, f_b, e_b, a_b,
            Mkt, fWbt, eWt, aWt, Wo, EA, Ko, outTrue, t0, Tc);
        fused_kernel<<<BB, 256, 0, stream>>>(
            Wo, EA, Mv0, Ko, fWat, p_W, p_b, pred, MvWS,
            t0, Tc, t0 == 0 ? 1 : 0, (t0 + Tc < TT) ? 1 : 0);
    }
}

// Round 9
// 181.507 us; speedup vs baseline: 1.2996x; 1.2996x over previous
//
#include <hip/hip_runtime.h>
#include <math.h>

// Problem constants (fixed by setup_inputs)
#define BB 256      // batch
#define TT 256      // time steps
#define NQ 1000     // num_q
#define DK 128
#define DV 128
#define CC 32

typedef short s16x8 __attribute__((ext_vector_type(8)));   // 8 bf16 bit-patterns
typedef float f32x4 __attribute__((ext_vector_type(4)));
typedef float f32x2 __attribute__((ext_vector_type(2)));

__device__ __forceinline__ float fast_sigmoid(float x) {
    x = fminf(fmaxf(x, -30.f), 30.f);
    return 1.f / (1.f + __expf(-x));
}
__device__ __forceinline__ float fast_tanh(float x) {
    x = fminf(fmaxf(x, -15.f), 15.f);
    float t = __expf(2.f * x);
    return (t - 1.f) / (t + 1.f);
}
__device__ __forceinline__ unsigned short f2bf(float f) {   // RNE fp32->bf16
    unsigned u = __float_as_uint(f);
    u += 0x7fffu + ((u >> 16) & 1u);
    return (unsigned short)(u >> 16);
}
__device__ __forceinline__ float bf2f(unsigned short h) {
    return __uint_as_float((unsigned)h << 16);
}
__device__ __forceinline__ unsigned u4get(uint4 v, int i) { // i constant after unroll
    return i == 0 ? v.x : i == 1 ? v.y : i == 2 ? v.z : v.w;
}
__device__ __forceinline__ f32x2 mk2(float x, float y) { f32x2 r; r.x = x; r.y = y; return r; }
__device__ __forceinline__ f32x2 fma2(f32x2 a, f32x2 b, f32x2 c) {
    return __builtin_elementwise_fma(a, b, c);
}

// ---------------------------------------------------------------------------
// conv_kernel: build bf16 TRANSPOSED weights in ws (B-operand layout Wt[n][k])
// ---------------------------------------------------------------------------
__global__ __launch_bounds__(256) void conv_kernel(
    const float* __restrict__ eW, const float* __restrict__ aW,
    const float* __restrict__ fW, const float* __restrict__ Mk,
    unsigned short* __restrict__ eWt, unsigned short* __restrict__ aWt,
    unsigned short* __restrict__ fWat, unsigned short* __restrict__ fWbt,
    unsigned short* __restrict__ Mkt)
{
    int idx = blockIdx.x * 256 + threadIdx.x;
    if (idx < 16384) {
        int n = idx >> 7, k = idx & 127;
        eWt[idx] = f2bf(eW[k * 128 + n]);
    } else if (idx < 32768) {
        int i = idx - 16384; int n = i >> 7, k = i & 127;
        aWt[i] = f2bf(aW[k * 128 + n]);
    } else if (idx < 49152) {
        int i = idx - 32768; int n = i >> 7, k = i & 127;
        fWat[i] = f2bf(fW[k * 128 + n]);
    } else if (idx < 65536) {
        int i = idx - 49152; int n = i >> 7, k = i & 127;
        fWbt[i] = f2bf(fW[(128 + k) * 128 + n]);
    } else if (idx < 69632) {
        int i = idx - 65536; int n = i >> 7, k = i & 127;   // n=c 0..31
        Mkt[i] = f2bf(Mk[k * 32 + n]);
    }
}

// ---------------------------------------------------------------------------
// MFMA helper: wave computes 16 rows x (NT*16) cols, K=128.
// ---------------------------------------------------------------------------
template <int NT, class F>
__device__ __forceinline__ void mfma_phase(const unsigned short* Wlds,
                                           const s16x8 (&aF)[4], int lane, F emit)
{
    const int quad = lane >> 4, nrow = lane & 15;
#pragma unroll
    for (int nt = 0; nt < NT; ++nt) {
        f32x4 acc = {0.f, 0.f, 0.f, 0.f};
#pragma unroll
        for (int kb = 0; kb < 4; ++kb) {
            s16x8 bf = *(const s16x8*)&Wlds[(nt * 16 + nrow) * 136 + kb * 32 + quad * 8];
            acc = __builtin_amdgcn_mfma_f32_16x16x32_bf16(aF[kb], bf, acc, 0, 0, 0);
        }
        int col = nt * 16 + nrow;
        emit(quad * 4 + 0, col, acc[0]);
        emit(quad * 4 + 1, col, acc[1]);
        emit(quad * 4 + 2, col, acc[2]);
        emit(quad * 4 + 3, col, acc[3]);
    }
}

// ---------------------------------------------------------------------------
// pre_kernel (MFMA, unchanged from R7)
// ---------------------------------------------------------------------------
__global__ __launch_bounds__(256) void pre_kernel(
    const int* __restrict__ skills, const int* __restrict__ responses,
    const float* __restrict__ k_emb, const float* __restrict__ v_emb,
    const float* __restrict__ fb, const float* __restrict__ eb,
    const float* __restrict__ ab,
    const unsigned short* __restrict__ Mkt, const unsigned short* __restrict__ fWbt,
    const unsigned short* __restrict__ eWt, const unsigned short* __restrict__ aWt,
    float* __restrict__ Wo, unsigned* __restrict__ EA,
    unsigned short* __restrict__ Ko, float* __restrict__ outTrue,
    int t0, int Tc)
{
    const int tid = threadIdx.x;
    const int lane = tid & 63;
    const int m_base = (tid >> 6) * 16;
    const int mrow = lane & 15, quad = lane >> 4;
    const size_t base = (size_t)blockIdx.x * 64;

    __shared__ __align__(16) unsigned short Albs[64 * 136];
    __shared__ __align__(16) unsigned short Wlds[128 * 136];
    __shared__ float lg[64 * 33];
    __shared__ int sIdx[64], qIdx[64];

    if (tid < 64) {
        int flat = (int)base + tid;
        int b = flat / Tc, tcc = flat % Tc;
        int t = t0 + tcc;
        int gi = b * TT + t;
        int s = skills[gi];
        int r = responses[gi];
        sIdx[tid] = s;
        qIdx[tid] = s + NQ * ((r > -1) ? r : 0);
        if (t >= 1) outTrue[b * (TT - 1) + (t - 1)] = (float)r;
    }
    __syncthreads();

    {
        int row = tid >> 2, c0 = (tid & 3) * 32;
        int s = sIdx[row];
        const float* src = k_emb + (size_t)s * DK + c0;
#pragma unroll
        for (int j = 0; j < 8; ++j) {
            float4 v = *(const float4*)(src + j * 4);
            unsigned short* dp = &Albs[row * 136 + c0 + j * 4];
            dp[0] = f2bf(v.x); dp[1] = f2bf(v.y); dp[2] = f2bf(v.z); dp[3] = f2bf(v.w);
        }
        int n = tid >> 3, k0 = (tid & 7) * 16;
        *(s16x8*)&Wlds[n * 136 + k0]     = *(const s16x8*)&Mkt[n * 128 + k0];
        *(s16x8*)&Wlds[n * 136 + k0 + 8] = *(const s16x8*)&Mkt[n * 128 + k0 + 8];
    }
    __syncthreads();

    s16x8 aF[4];
#pragma unroll
    for (int kb = 0; kb < 4; ++kb)
        aF[kb] = *(const s16x8*)&Albs[(m_base + mrow) * 136 + kb * 32 + quad * 8];
    mfma_phase<2>(Wlds, aF, lane, [&](int ml, int col, float x) {
        lg[(m_base + ml) * 33 + col] = x;
    });
    __syncthreads();

    {
        int n = tid >> 1, k0 = (tid & 1) * 64;
#pragma unroll
        for (int j = 0; j < 8; ++j)
            *(s16x8*)&Wlds[n * 136 + k0 + j * 8] = *(const s16x8*)&fWbt[n * 128 + k0 + j * 8];
    }
    if (tid < 64) {
        float m = -1e30f;
#pragma unroll
        for (int c = 0; c < CC; ++c) m = fmaxf(m, lg[tid * 33 + c]);
        float ex[CC]; float sum = 0.f;
#pragma unroll
        for (int c = 0; c < CC; ++c) { ex[c] = __expf(lg[tid * 33 + c] - m); sum += ex[c]; }
        float inv = 1.f / sum;
        float* wp = Wo + (base + tid) * CC;
#pragma unroll
        for (int c = 0; c < CC; c += 4)
            *(float4*)(wp + c) = make_float4(ex[c] * inv, ex[c + 1] * inv,
                                             ex[c + 2] * inv, ex[c + 3] * inv);
    }
    __syncthreads();

    mfma_phase<8>(Wlds, aF, lane, [&](int ml, int col, float x) {
        size_t r = base + m_base + ml;
        Ko[r * 128 + col] = f2bf(x + fb[col]);
    });
    __syncthreads();

    {
        int row = tid >> 2, c0 = (tid & 3) * 32;
        int q = qIdx[row];
        const float* src = v_emb + (size_t)q * DV + c0;
#pragma unroll
        for (int j = 0; j < 8; ++j) {
            float4 v = *(const float4*)(src + j * 4);
            unsigned short* dp = &Albs[row * 136 + c0 + j * 4];
            dp[0] = f2bf(v.x); dp[1] = f2bf(v.y); dp[2] = f2bf(v.z); dp[3] = f2bf(v.w);
        }
        int n = tid >> 1, k0 = (tid & 1) * 64;
#pragma unroll
        for (int j = 0; j < 8; ++j)
            *(s16x8*)&Wlds[n * 136 + k0 + j * 8] = *(const s16x8*)&eWt[n * 128 + k0 + j * 8];
    }
    __syncthreads();

#pragma unroll
    for (int kb = 0; kb < 4; ++kb)
        aF[kb] = *(const s16x8*)&Albs[(m_base + mrow) * 136 + kb * 32 + quad * 8];
    // phase 6: et -> Albs (vt frags already in regs)
    mfma_phase<8>(Wlds, aF, lane, [&](int ml, int col, float x) {
        Albs[(m_base + ml) * 136 + col] = f2bf(fast_sigmoid(x + eb[col]));
    });
    __syncthreads();

    {
        int n = tid >> 1, k0 = (tid & 1) * 64;
#pragma unroll
        for (int j = 0; j < 8; ++j)
            *(s16x8*)&Wlds[n * 136 + k0 + j * 8] = *(const s16x8*)&aWt[n * 128 + k0 + j * 8];
    }
    __syncthreads();

    // phase 8: at + pack(et,at) -> one 4B store
    mfma_phase<8>(Wlds, aF, lane, [&](int ml, int col, float x) {
        size_t r = base + m_base + ml;
        int bb = (int)(r / (size_t)Tc);
        int t  = (int)(r - (size_t)bb * Tc);
        size_t o4 = (((size_t)bb * (Tc >> 5) + (t >> 5)) * 8 + ((t >> 2) & 7)) * 128 + col;
        unsigned lo = Albs[(m_base + ml) * 136 + col];
        unsigned hi = (unsigned)f2bf(fast_tanh(x + ab[col])) << 16;
        EA[o4 * 4 + (t & 3)] = hi | lo;
    });
}

// ---------------------------------------------------------------------------
// fused_kernel v3 (seq + post) — R9:
//  * REVERT R8's w register-prefetch (VGPR demand 160+ vs allocator's ~108
//    ceiling -> scratch spill on the critical path; third confirmation that
//    large explicitly-pipelined register state spills on this toolchain).
//    w is read from LDS at use (R7 form, 56 us); compiler schedules lgkmcnt.
//  * KEEP R8's RSTR=140 padding (proven: conflicts 655K -> 65K) so consumer
//    fragment reads stop stealing LDS-pipe cycles from the producer chain.
// Live set: Mv2(32) + erA(32) + erB(32) + wr(8) = 104 VGPR — the exact
// footprint the allocator accepted in R7.
// ---------------------------------------------------------------------------

#define CH 32
#define WROW 36     // Wl row stride (floats)
#define RSTR 140    // rtl/fWl row stride (shorts): 70 dw = 6 mod 32

#define LOAD_W(gg) do {                                                       \
    const float* ws = Wb + (size_t)(gg) * CH * 32;                            \
    wr0 = *(const float4*)(ws + tid * 8);                                     \
    wr1 = *(const float4*)(ws + tid * 8 + 4);                                 \
} while (0)

#define PUB_W(gg) do {                                                        \
    float* wd = &Wl[(gg) & 1][lr * WROW + lq * 8];                            \
    *(float4*)wd = wr0; *(float4*)(wd + 4) = wr1;                             \
} while (0)

#define LOAD_EA(ER, gg) do {                                                  \
    const uint4* src = EA4 + ((size_t)(bq + (gg))) * 1024 + tid;              \
    _Pragma("unroll")                                                         \
    for (int j = 0; j < 8; ++j) ER[j] = src[j * 128];                         \
} while (0)

#define SEQ_CHUNK(ER, gg, SL) do {                                            \
    const float* wlc = Wl[(gg) & 1];                                          \
    unsigned short* slp = SL;                                                 \
    _Pragma("unroll")                                                         \
    for (int tl = 0; tl < CH; ++tl) {                                         \
        const float* wrow = wlc + tl * WROW;                                  \
        float4 wqa = *(const float4*)(wrow + 0);                              \
        float4 wqb = *(const float4*)(wrow + 4);                              \
        float4 wqc = *(const float4*)(wrow + 8);                              \
        float4 wqd = *(const float4*)(wrow + 12);                             \
        float4 wqe = *(const float4*)(wrow + 16);                             \
        float4 wqf = *(const float4*)(wrow + 20);                             \
        float4 wqg = *(const float4*)(wrow + 24);                             \
        float4 wqh = *(const float4*)(wrow + 28);                             \
        f32x2 w2[16];                                                         \
        w2[0]  = mk2(wqa.x, wqa.y); w2[1]  = mk2(wqa.z, wqa.w);               \
        w2[2]  = mk2(wqb.x, wqb.y); w2[3]  = mk2(wqb.z, wqb.w);               \
        w2[4]  = mk2(wqc.x, wqc.y); w2[5]  = mk2(wqc.z, wqc.w);               \
        w2[6]  = mk2(wqd.x, wqd.y); w2[7]  = mk2(wqd.z, wqd.w);               \
        w2[8]  = mk2(wqe.x, wqe.y); w2[9]  = mk2(wqe.z, wqe.w);               \
        w2[10] = mk2(wqf.x, wqf.y); w2[11] = mk2(wqf.z, wqf.w);               \
        w2[12] = mk2(wqg.x, wqg.y); w2[13] = mk2(wqg.z, wqg.w);               \
        w2[14] = mk2(wqh.x, wqh.y); w2[15] = mk2(wqh.z, wqh.w);               \
        unsigned ea = u4get(ER[tl >> 2], tl & 3);                             \
        float e = __uint_as_float(ea << 16);                                  \
        float a = __uint_as_float(ea & 0xffff0000u);                          \
        f32x2 ne2 = mk2(-e, -e);                                              \
        f32x2 a2  = mk2(a, a);                                                \
        f32x2 r0 = mk2(0.f, 0.f), r1 = r0, r2 = r0, r3 = r0;                  \
        _Pragma("unroll")                                                     \
        for (int q = 0; q < 4; ++q) {                                         \
            r0 = fma2(w2[4*q+0], Mv2[4*q+0], r0);                             \
            r1 = fma2(w2[4*q+1], Mv2[4*q+1], r1);                             \
            r2 = fma2(w2[4*q+2], Mv2[4*q+2], r2);                             \
            r3 = fma2(w2[4*q+3], Mv2[4*q+3], r3);                             \
        }                                                                     \
        f32x2 rs = (r0 + r1) + (r2 + r3);                                     \
        slp[tl * RSTR + tid] = f2bf(rs.x + rs.y);                             \
        _Pragma("unroll")                                                     \
        for (int i = 0; i < 16; ++i)                                          \
            Mv2[i] = fma2(w2[i], fma2(ne2, Mv2[i], a2), Mv2[i]);              \
    }                                                                         \
} while (0)

__device__ __forceinline__ void consume_chunk(
    int gc, const unsigned short* sl, const unsigned short* fWl,
    int b, int Tc, int t0,
    const unsigned short* __restrict__ Ko, const float* __restrict__ pW,
    float pbv, float* __restrict__ pred, int tid)
{
    const int lane = tid & 63;
    const int cw = (tid >> 6) & 1;          // consumer wave 0/1 -> rows cw*16..+15
    const int mrow = lane & 15, quad = lane >> 4;
    s16x8 aF[4];
#pragma unroll
    for (int kb = 0; kb < 4; ++kb)
        aF[kb] = *(const s16x8*)&sl[(cw * 16 + mrow) * RSTR + kb * 32 + quad * 8];
    float p0 = 0.f, p1 = 0.f, p2 = 0.f, p3 = 0.f;
    size_t rbase = (size_t)b * Tc + gc * CH + cw * 16 + quad * 4;
#pragma unroll
    for (int nt = 0; nt < 8; ++nt) {
        f32x4 acc = {0.f, 0.f, 0.f, 0.f};
#pragma unroll
        for (int kb = 0; kb < 4; ++kb) {
            s16x8 bf = *(const s16x8*)&fWl[(nt * 16 + mrow) * RSTR + kb * 32 + quad * 8];
            acc = __builtin_amdgcn_mfma_f32_16x16x32_bf16(aF[kb], bf, acc, 0, 0, 0);
        }
        int col = nt * 16 + mrow;
        float pw = pW[col];
        p0 = fmaf(fast_tanh(acc[0] + bf2f(Ko[(rbase + 0) * 128 + col])), pw, p0);
        p1 = fmaf(fast_tanh(acc[1] + bf2f(Ko[(rbase + 1) * 128 + col])), pw, p1);
        p2 = fmaf(fast_tanh(acc[2] + bf2f(Ko[(rbase + 2) * 128 + col])), pw, p2);
        p3 = fmaf(fast_tanh(acc[3] + bf2f(Ko[(rbase + 3) * 128 + col])), pw, p3);
    }
#pragma unroll
    for (int off = 1; off < 16; off <<= 1) {
        p0 += __shfl_xor(p0, off, 64); p1 += __shfl_xor(p1, off, 64);
        p2 += __shfl_xor(p2, off, 64); p3 += __shfl_xor(p3, off, 64);
    }
    if (mrow == 0) {
        int tb = t0 + gc * CH + cw * 16 + quad * 4;
        float ps[4] = {p0, p1, p2, p3};
#pragma unroll
        for (int reg = 0; reg < 4; ++reg) {
            int t = tb + reg;
            if (t < TT - 1) pred[b * (TT - 1) + t] = fast_sigmoid(ps[reg] + pbv);
        }
    }
}

__global__ __launch_bounds__(256, 1) void fused_kernel(
    const float* __restrict__ W, const unsigned* __restrict__ EA,
    const float* __restrict__ Mv0, const unsigned short* __restrict__ Ko,
    const unsigned short* __restrict__ fWat, const float* __restrict__ pW,
    const float* __restrict__ pb,
    float* __restrict__ pred, float* __restrict__ MvWS,
    int t0, int Tc, int doInit, int doSave)
{
    const int b = blockIdx.x;
    const int tid = threadIdx.x;
    const int nch = Tc / CH;

    __shared__ __align__(16) float Wl[2][CH * WROW];            //  9.2 KB
    __shared__ __align__(16) unsigned short rtl[2][CH * RSTR];  // 17.9 KB
    __shared__ __align__(16) unsigned short fWl[128 * RSTR];    // 35.8 KB

    // stage fWat -> fWl (all 256 threads)
    {
        int n = tid >> 1, k0 = (tid & 1) * 64;
#pragma unroll
        for (int j = 0; j < 8; ++j)
            *(s16x8*)&fWl[n * RSTR + k0 + j * 8] = *(const s16x8*)&fWat[n * 128 + k0 + j * 8];
    }

    const int lr = tid >> 2, lq = tid & 3;
    const float* __restrict__ Wb = W + (size_t)b * Tc * 32;
    const uint4* __restrict__ EA4 = (const uint4*)EA;
    const int bq = b * nch;
    f32x2 Mv2[16];
    float4 wr0, wr1;
    uint4 erA[8], erB[8];
    float pbv = 0.f;

    if (tid < 128) {
        if (doInit) {
#pragma unroll
            for (int i = 0; i < 16; ++i)
                Mv2[i] = mk2(Mv0[(2 * i) * 128 + tid], Mv0[(2 * i + 1) * 128 + tid]);
        } else {
#pragma unroll
            for (int i = 0; i < 16; ++i)
                Mv2[i] = mk2(MvWS[(size_t)b * 4096 + (2 * i) * 128 + tid],
                             MvWS[(size_t)b * 4096 + (2 * i + 1) * 128 + tid]);
        }
        LOAD_W(0); PUB_W(0);
        LOAD_EA(erA, 0);
        if (nch > 1) LOAD_W(1);
    } else {
        pbv = pb[0];
    }
    __syncthreads();

    for (int g = 0; g < nch; g += 2) {
        // ---- even chunk g: produce -> slot0; consume chunk g-1 (slot1) ----
        if (tid < 128) {
            if (g + 1 < nch) PUB_W(g + 1);
            if (g + 2 < nch) LOAD_W(g + 2);
            if (g + 1 < nch) LOAD_EA(erB, g + 1);
            SEQ_CHUNK(erA, g, rtl[0]);
        } else if (g >= 1) {
            consume_chunk(g - 1, rtl[1], fWl, b, Tc, t0, Ko, pW, pbv, pred, tid);
        }
        __syncthreads();

        // ---- odd chunk g+1: produce -> slot1; consume chunk g (slot0) ----
        if (tid < 128) {
            if (g + 1 < nch) {
                if (g + 2 < nch) PUB_W(g + 2);
                if (g + 3 < nch) LOAD_W(g + 3);
                if (g + 2 < nch) LOAD_EA(erA, g + 2);
                SEQ_CHUNK(erB, g + 1, rtl[1]);
            }
        } else {
            consume_chunk(g, rtl[0], fWl, b, Tc, t0, Ko, pW, pbv, pred, tid);
        }
        __syncthreads();
    }
    // epilogue: for even nch the last (odd) chunk is still unconsumed
    if (!(nch & 1) && tid >= 128) {
        consume_chunk(nch - 1, rtl[1], fWl, b, Tc, t0, Ko, pW, pbv, pred, tid);
    }

    if (doSave && tid < 128) {
#pragma unroll
        for (int i = 0; i < 16; ++i) {
            MvWS[(size_t)b * 4096 + (2 * i) * 128 + tid]     = Mv2[i].x;
            MvWS[(size_t)b * 4096 + (2 * i + 1) * 128 + tid] = Mv2[i].y;
        }
    }
}

// ---------------------------------------------------------------------------

extern "C" void kernel_launch(void* const* d_in, const int* in_sizes, int n_in,
                              void* d_out, int out_size, void* d_ws, size_t ws_size,
                              hipStream_t stream) {
    const int*   skills    = (const int*)d_in[0];
    const int*   responses = (const int*)d_in[1];
    const float* k_emb     = (const float*)d_in[2];
    const float* v_emb     = (const float*)d_in[3];
    const float* Mk        = (const float*)d_in[4];
    const float* Mv0       = (const float*)d_in[5];
    const float* f_W       = (const float*)d_in[6];
    const float* f_b       = (const float*)d_in[7];
    const float* p_W       = (const float*)d_in[8];
    const float* p_b       = (const float*)d_in[9];
    const float* e_W       = (const float*)d_in[10];
    const float* e_b       = (const float*)d_in[11];
    const float* a_W       = (const float*)d_in[12];
    const float* a_b       = (const float*)d_in[13];

    float* pred    = (float*)d_out;                 // [256][255]
    float* outTrue = pred + BB * (TT - 1);          // [256][255]

    // scratch per row: Wo 128 B + EA 512 B + Ko 256 B = 896 B
    int Tc = TT;
    for (;;) {
        size_t need = (size_t)BB * Tc * 896 + 69632 * 2;
        if (Tc < TT) need += (size_t)BB * 4096 * 4;
        if (need <= ws_size || Tc <= 32) break;
        Tc >>= 1;
    }

    char* p = (char*)d_ws;
    float* Wo = (float*)p;                     p += (size_t)BB * Tc * 32 * 4;
    unsigned* EA = (unsigned*)p;               p += (size_t)BB * Tc * 128 * 4;
    unsigned short* Ko = (unsigned short*)p;   p += (size_t)BB * Tc * 128 * 2;
    unsigned short* eWt = (unsigned short*)p;  p += 16384 * 2;
    unsigned short* aWt = (unsigned short*)p;  p += 16384 * 2;
    unsigned short* fWat = (unsigned short*)p; p += 16384 * 2;
    unsigned short* fWbt = (unsigned short*)p; p += 16384 * 2;
    unsigned short* Mkt = (unsigned short*)p;  p += 4096 * 2;
    float* MvWS = (float*)p;

    conv_kernel<<<272, 256, 0, stream>>>(e_W, a_W, f_W, Mk,
                                         eWt, aWt, fWat, fWbt, Mkt);

    for (int t0 = 0; t0 < TT; t0 += Tc) {
        pre_kernel<<<(BB * Tc) / 64, 256, 0, stream>>>(
            skills, responses, k_emb, v_emb, f_b, e_b, a_b,
            Mkt, fWbt, eWt, aWt, Wo, EA, Ko, outTrue, t0, Tc);
        fused_kernel<<<BB, 256, 0, stream>>>(
            Wo, EA, Mv0, Ko, fWat, p_W, p_b, pred, MvWS,
            t0, Tc, t0 == 0 ? 1 : 0, (t0 + Tc < TT) ? 1 : 0);
    }
}

// Round 10
// 174.045 us; speedup vs baseline: 1.3553x; 1.0429x over previous
//
#include <hip/hip_runtime.h>
#include <math.h>

// Problem constants (fixed by setup_inputs)
#define BB 256      // batch
#define TT 256      // time steps
#define NQ 1000     // num_q
#define DK 128
#define DV 128
#define CC 32

typedef short s16x8 __attribute__((ext_vector_type(8)));   // 8 bf16 bit-patterns
typedef float f32x4 __attribute__((ext_vector_type(4)));
typedef float f32x2 __attribute__((ext_vector_type(2)));

__device__ __forceinline__ float fast_sigmoid(float x) {
    x = fminf(fmaxf(x, -30.f), 30.f);
    return 1.f / (1.f + __expf(-x));
}
__device__ __forceinline__ float fast_tanh(float x) {
    x = fminf(fmaxf(x, -15.f), 15.f);
    float t = __expf(2.f * x);
    return (t - 1.f) / (t + 1.f);
}
__device__ __forceinline__ unsigned short f2bf(float f) {   // RNE fp32->bf16
    unsigned u = __float_as_uint(f);
    u += 0x7fffu + ((u >> 16) & 1u);
    return (unsigned short)(u >> 16);
}
__device__ __forceinline__ float bf2f(unsigned short h) {
    return __uint_as_float((unsigned)h << 16);
}
__device__ __forceinline__ unsigned u4get(uint4 v, int i) { // i constant after unroll
    return i == 0 ? v.x : i == 1 ? v.y : i == 2 ? v.z : v.w;
}
__device__ __forceinline__ f32x2 mk2(float x, float y) { f32x2 r; r.x = x; r.y = y; return r; }
__device__ __forceinline__ f32x2 fma2(f32x2 a, f32x2 b, f32x2 c) {
    return __builtin_elementwise_fma(a, b, c);
}

// ---------------------------------------------------------------------------
// conv_kernel: build bf16 TRANSPOSED weights in ws (B-operand layout Wt[n][k])
// ---------------------------------------------------------------------------
__global__ __launch_bounds__(256) void conv_kernel(
    const float* __restrict__ eW, const float* __restrict__ aW,
    const float* __restrict__ fW, const float* __restrict__ Mk,
    unsigned short* __restrict__ eWt, unsigned short* __restrict__ aWt,
    unsigned short* __restrict__ fWat, unsigned short* __restrict__ fWbt,
    unsigned short* __restrict__ Mkt)
{
    int idx = blockIdx.x * 256 + threadIdx.x;
    if (idx < 16384) {
        int n = idx >> 7, k = idx & 127;
        eWt[idx] = f2bf(eW[k * 128 + n]);
    } else if (idx < 32768) {
        int i = idx - 16384; int n = i >> 7, k = i & 127;
        aWt[i] = f2bf(aW[k * 128 + n]);
    } else if (idx < 49152) {
        int i = idx - 32768; int n = i >> 7, k = i & 127;
        fWat[i] = f2bf(fW[k * 128 + n]);
    } else if (idx < 65536) {
        int i = idx - 49152; int n = i >> 7, k = i & 127;
        fWbt[i] = f2bf(fW[(128 + k) * 128 + n]);
    } else if (idx < 69632) {
        int i = idx - 65536; int n = i >> 7, k = i & 127;   // n=c 0..31
        Mkt[i] = f2bf(Mk[k * 32 + n]);
    }
}

// ---------------------------------------------------------------------------
// MFMA helper: wave computes 16 rows x (NT*16) cols, K=128.
// ---------------------------------------------------------------------------
template <int NT, class F>
__device__ __forceinline__ void mfma_phase(const unsigned short* Wlds,
                                           const s16x8 (&aF)[4], int lane, F emit)
{
    const int quad = lane >> 4, nrow = lane & 15;
#pragma unroll
    for (int nt = 0; nt < NT; ++nt) {
        f32x4 acc = {0.f, 0.f, 0.f, 0.f};
#pragma unroll
        for (int kb = 0; kb < 4; ++kb) {
            s16x8 bf = *(const s16x8*)&Wlds[(nt * 16 + nrow) * 136 + kb * 32 + quad * 8];
            acc = __builtin_amdgcn_mfma_f32_16x16x32_bf16(aF[kb], bf, acc, 0, 0, 0);
        }
        int col = nt * 16 + nrow;
        emit(quad * 4 + 0, col, acc[0]);
        emit(quad * 4 + 1, col, acc[1]);
        emit(quad * 4 + 2, col, acc[2]);
        emit(quad * 4 + 3, col, acc[3]);
    }
}

// ---------------------------------------------------------------------------
// pre_kernel (MFMA, unchanged from R7)
// ---------------------------------------------------------------------------
__global__ __launch_bounds__(256) void pre_kernel(
    const int* __restrict__ skills, const int* __restrict__ responses,
    const float* __restrict__ k_emb, const float* __restrict__ v_emb,
    const float* __restrict__ fb, const float* __restrict__ eb,
    const float* __restrict__ ab,
    const unsigned short* __restrict__ Mkt, const unsigned short* __restrict__ fWbt,
    const unsigned short* __restrict__ eWt, const unsigned short* __restrict__ aWt,
    float* __restrict__ Wo, unsigned* __restrict__ EA,
    unsigned short* __restrict__ Ko, float* __restrict__ outTrue,
    int t0, int Tc)
{
    const int tid = threadIdx.x;
    const int lane = tid & 63;
    const int m_base = (tid >> 6) * 16;
    const int mrow = lane & 15, quad = lane >> 4;
    const size_t base = (size_t)blockIdx.x * 64;

    __shared__ __align__(16) unsigned short Albs[64 * 136];
    __shared__ __align__(16) unsigned short Wlds[128 * 136];
    __shared__ float lg[64 * 33];
    __shared__ int sIdx[64], qIdx[64];

    if (tid < 64) {
        int flat = (int)base + tid;
        int b = flat / Tc, tcc = flat % Tc;
        int t = t0 + tcc;
        int gi = b * TT + t;
        int s = skills[gi];
        int r = responses[gi];
        sIdx[tid] = s;
        qIdx[tid] = s + NQ * ((r > -1) ? r : 0);
        if (t >= 1) outTrue[b * (TT - 1) + (t - 1)] = (float)r;
    }
    __syncthreads();

    {
        int row = tid >> 2, c0 = (tid & 3) * 32;
        int s = sIdx[row];
        const float* src = k_emb + (size_t)s * DK + c0;
#pragma unroll
        for (int j = 0; j < 8; ++j) {
            float4 v = *(const float4*)(src + j * 4);
            unsigned short* dp = &Albs[row * 136 + c0 + j * 4];
            dp[0] = f2bf(v.x); dp[1] = f2bf(v.y); dp[2] = f2bf(v.z); dp[3] = f2bf(v.w);
        }
        int n = tid >> 3, k0 = (tid & 7) * 16;
        *(s16x8*)&Wlds[n * 136 + k0]     = *(const s16x8*)&Mkt[n * 128 + k0];
        *(s16x8*)&Wlds[n * 136 + k0 + 8] = *(const s16x8*)&Mkt[n * 128 + k0 + 8];
    }
    __syncthreads();

    s16x8 aF[4];
#pragma unroll
    for (int kb = 0; kb < 4; ++kb)
        aF[kb] = *(const s16x8*)&Albs[(m_base + mrow) * 136 + kb * 32 + quad * 8];
    mfma_phase<2>(Wlds, aF, lane, [&](int ml, int col, float x) {
        lg[(m_base + ml) * 33 + col] = x;
    });
    __syncthreads();

    {
        int n = tid >> 1, k0 = (tid & 1) * 64;
#pragma unroll
        for (int j = 0; j < 8; ++j)
            *(s16x8*)&Wlds[n * 136 + k0 + j * 8] = *(const s16x8*)&fWbt[n * 128 + k0 + j * 8];
    }
    if (tid < 64) {
        float m = -1e30f;
#pragma unroll
        for (int c = 0; c < CC; ++c) m = fmaxf(m, lg[tid * 33 + c]);
        float ex[CC]; float sum = 0.f;
#pragma unroll
        for (int c = 0; c < CC; ++c) { ex[c] = __expf(lg[tid * 33 + c] - m); sum += ex[c]; }
        float inv = 1.f / sum;
        float* wp = Wo + (base + tid) * CC;
#pragma unroll
        for (int c = 0; c < CC; c += 4)
            *(float4*)(wp + c) = make_float4(ex[c] * inv, ex[c + 1] * inv,
                                             ex[c + 2] * inv, ex[c + 3] * inv);
    }
    __syncthreads();

    mfma_phase<8>(Wlds, aF, lane, [&](int ml, int col, float x) {
        size_t r = base + m_base + ml;
        Ko[r * 128 + col] = f2bf(x + fb[col]);
    });
    __syncthreads();

    {
        int row = tid >> 2, c0 = (tid & 3) * 32;
        int q = qIdx[row];
        const float* src = v_emb + (size_t)q * DV + c0;
#pragma unroll
        for (int j = 0; j < 8; ++j) {
            float4 v = *(const float4*)(src + j * 4);
            unsigned short* dp = &Albs[row * 136 + c0 + j * 4];
            dp[0] = f2bf(v.x); dp[1] = f2bf(v.y); dp[2] = f2bf(v.z); dp[3] = f2bf(v.w);
        }
        int n = tid >> 1, k0 = (tid & 1) * 64;
#pragma unroll
        for (int j = 0; j < 8; ++j)
            *(s16x8*)&Wlds[n * 136 + k0 + j * 8] = *(const s16x8*)&eWt[n * 128 + k0 + j * 8];
    }
    __syncthreads();

#pragma unroll
    for (int kb = 0; kb < 4; ++kb)
        aF[kb] = *(const s16x8*)&Albs[(m_base + mrow) * 136 + kb * 32 + quad * 8];
    // phase 6: et -> Albs (vt frags already in regs)
    mfma_phase<8>(Wlds, aF, lane, [&](int ml, int col, float x) {
        Albs[(m_base + ml) * 136 + col] = f2bf(fast_sigmoid(x + eb[col]));
    });
    __syncthreads();

    {
        int n = tid >> 1, k0 = (tid & 1) * 64;
#pragma unroll
        for (int j = 0; j < 8; ++j)
            *(s16x8*)&Wlds[n * 136 + k0 + j * 8] = *(const s16x8*)&aWt[n * 128 + k0 + j * 8];
    }
    __syncthreads();

    // phase 8: at + pack(et,at) -> one 4B store
    mfma_phase<8>(Wlds, aF, lane, [&](int ml, int col, float x) {
        size_t r = base + m_base + ml;
        int bb = (int)(r / (size_t)Tc);
        int t  = (int)(r - (size_t)bb * Tc);
        size_t o4 = (((size_t)bb * (Tc >> 5) + (t >> 5)) * 8 + ((t >> 2) & 7)) * 128 + col;
        unsigned lo = Albs[(m_base + ml) * 136 + col];
        unsigned hi = (unsigned)f2bf(fast_tanh(x + ab[col])) << 16;
        EA[o4 * 4 + (t & 3)] = hi | lo;
    });
}

// ---------------------------------------------------------------------------
// fused_kernel v4 (seq + post) — R10:
//  * RSTR reverted 140 -> 136: R9's clean A/B showed the padding HURT
//    (56 -> 62 us) — 140-short rows are only 8B-aligned on odd rows, so
//    consumer s16x8 reads stop being single ds_read_b128; the conflicts it
//    removed were consumer-side slack, not producer critical path.
//  * w software pipeline with INDIVIDUALLY NAMED float4 vars (w0..w7 /
//    u0..u7, even/odd step bodies) — R8's arrays failed SROA and went to
//    scratch (VGPR=108 + 2x slowdown); named scalars cannot. Prefetch
//    distance = 1 step (~160 cyc compute covers ~120 cyc ds_read latency).
//    Live set ~180 VGPR — R6 precedent (164 allocated cleanly).
// ---------------------------------------------------------------------------

#define CH 32
#define WROW 36     // Wl row stride (floats)
#define RSTR 136    // rtl/fWl row stride (shorts) — R7-proven

#define LOAD_W(gg) do {                                                       \
    const float* ws = Wb + (size_t)(gg) * CH * 32;                            \
    wr0 = *(const float4*)(ws + tid * 8);                                     \
    wr1 = *(const float4*)(ws + tid * 8 + 4);                                 \
} while (0)

#define PUB_W(gg) do {                                                        \
    float* wd = &Wl[(gg) & 1][lr * WROW + lq * 8];                            \
    *(float4*)wd = wr0; *(float4*)(wd + 4) = wr1;                             \
} while (0)

#define LOAD_EA(ER, gg) do {                                                  \
    const uint4* src = EA4 + ((size_t)(bq + (gg))) * 1024 + tid;              \
    _Pragma("unroll")                                                         \
    for (int j = 0; j < 8; ++j) ER[j] = src[j * 128];                         \
} while (0)

// prefetch w row `rowidx` (compile-time after unroll) into 8 named float4s
#define PREF8(A0,A1,A2,A3,A4,A5,A6,A7, rowidx) do {                           \
    const float* _wr = wlc + (rowidx) * WROW;                                 \
    A0 = *(const float4*)(_wr + 0);  A1 = *(const float4*)(_wr + 4);          \
    A2 = *(const float4*)(_wr + 8);  A3 = *(const float4*)(_wr + 12);         \
    A4 = *(const float4*)(_wr + 16); A5 = *(const float4*)(_wr + 20);         \
    A6 = *(const float4*)(_wr + 24); A7 = *(const float4*)(_wr + 28);         \
} while (0)

// one chain step from 8 named register-resident float4s
#define STEP8(A0,A1,A2,A3,A4,A5,A6,A7, ER, tl) do {                           \
    f32x2 w2[16];                                                             \
    w2[0]  = mk2(A0.x, A0.y); w2[1]  = mk2(A0.z, A0.w);                       \
    w2[2]  = mk2(A1.x, A1.y); w2[3]  = mk2(A1.z, A1.w);                       \
    w2[4]  = mk2(A2.x, A2.y); w2[5]  = mk2(A2.z, A2.w);                       \
    w2[6]  = mk2(A3.x, A3.y); w2[7]  = mk2(A3.z, A3.w);                       \
    w2[8]  = mk2(A4.x, A4.y); w2[9]  = mk2(A4.z, A4.w);                       \
    w2[10] = mk2(A5.x, A5.y); w2[11] = mk2(A5.z, A5.w);                       \
    w2[12] = mk2(A6.x, A6.y); w2[13] = mk2(A6.z, A6.w);                       \
    w2[14] = mk2(A7.x, A7.y); w2[15] = mk2(A7.z, A7.w);                       \
    unsigned ea = u4get(ER[(tl) >> 2], (tl) & 3);                             \
    float e = __uint_as_float(ea << 16);                                      \
    float a = __uint_as_float(ea & 0xffff0000u);                              \
    f32x2 ne2 = mk2(-e, -e);                                                  \
    f32x2 a2  = mk2(a, a);                                                    \
    f32x2 r0 = mk2(0.f, 0.f), r1 = r0, r2 = r0, r3 = r0;                      \
    _Pragma("unroll")                                                         \
    for (int q = 0; q < 4; ++q) {                                             \
        r0 = fma2(w2[4*q+0], Mv2[4*q+0], r0);                                 \
        r1 = fma2(w2[4*q+1], Mv2[4*q+1], r1);                                 \
        r2 = fma2(w2[4*q+2], Mv2[4*q+2], r2);                                 \
        r3 = fma2(w2[4*q+3], Mv2[4*q+3], r3);                                 \
    }                                                                         \
    f32x2 rs = (r0 + r1) + (r2 + r3);                                         \
    slp[(tl) * RSTR + tid] = f2bf(rs.x + rs.y);                               \
    _Pragma("unroll")                                                         \
    for (int i = 0; i < 16; ++i)                                              \
        Mv2[i] = fma2(w2[i], fma2(ne2, Mv2[i], a2), Mv2[i]);                  \
} while (0)

// chunk: even steps compute from w0..w7, odd from u0..u7; prefetch 1 ahead
#define SEQ_CHUNK(ER, gg, SL) do {                                            \
    const float* wlc = Wl[(gg) & 1];                                          \
    unsigned short* slp = SL;                                                 \
    PREF8(w0,w1,w2_,w3_,w4_,w5_,w6_,w7_, 0);                                  \
    _Pragma("unroll")                                                         \
    for (int tp = 0; tp < 16; ++tp) {                                         \
        PREF8(u0,u1,u2,u3,u4,u5,u6,u7, 2 * tp + 1);                           \
        STEP8(w0,w1,w2_,w3_,w4_,w5_,w6_,w7_, ER, 2 * tp);                     \
        PREF8(w0,w1,w2_,w3_,w4_,w5_,w6_,w7_,                                  \
              (2 * tp + 2 < 32) ? (2 * tp + 2) : 31);                         \
        STEP8(u0,u1,u2,u3,u4,u5,u6,u7, ER, 2 * tp + 1);                       \
    }                                                                         \
} while (0)

__device__ __forceinline__ void consume_chunk(
    int gc, const unsigned short* sl, const unsigned short* fWl,
    int b, int Tc, int t0,
    const unsigned short* __restrict__ Ko, const float* __restrict__ pW,
    float pbv, float* __restrict__ pred, int tid)
{
    const int lane = tid & 63;
    const int cw = (tid >> 6) & 1;          // consumer wave 0/1 -> rows cw*16..+15
    const int mrow = lane & 15, quad = lane >> 4;
    s16x8 aF[4];
#pragma unroll
    for (int kb = 0; kb < 4; ++kb)
        aF[kb] = *(const s16x8*)&sl[(cw * 16 + mrow) * RSTR + kb * 32 + quad * 8];
    float p0 = 0.f, p1 = 0.f, p2 = 0.f, p3 = 0.f;
    size_t rbase = (size_t)b * Tc + gc * CH + cw * 16 + quad * 4;
#pragma unroll
    for (int nt = 0; nt < 8; ++nt) {
        f32x4 acc = {0.f, 0.f, 0.f, 0.f};
#pragma unroll
        for (int kb = 0; kb < 4; ++kb) {
            s16x8 bf = *(const s16x8*)&fWl[(nt * 16 + mrow) * RSTR + kb * 32 + quad * 8];
            acc = __builtin_amdgcn_mfma_f32_16x16x32_bf16(aF[kb], bf, acc, 0, 0, 0);
        }
        int col = nt * 16 + mrow;
        float pw = pW[col];
        p0 = fmaf(fast_tanh(acc[0] + bf2f(Ko[(rbase + 0) * 128 + col])), pw, p0);
        p1 = fmaf(fast_tanh(acc[1] + bf2f(Ko[(rbase + 1) * 128 + col])), pw, p1);
        p2 = fmaf(fast_tanh(acc[2] + bf2f(Ko[(rbase + 2) * 128 + col])), pw, p2);
        p3 = fmaf(fast_tanh(acc[3] + bf2f(Ko[(rbase + 3) * 128 + col])), pw, p3);
    }
#pragma unroll
    for (int off = 1; off < 16; off <<= 1) {
        p0 += __shfl_xor(p0, off, 64); p1 += __shfl_xor(p1, off, 64);
        p2 += __shfl_xor(p2, off, 64); p3 += __shfl_xor(p3, off, 64);
    }
    if (mrow == 0) {
        int tb = t0 + gc * CH + cw * 16 + quad * 4;
        float ps[4] = {p0, p1, p2, p3};
#pragma unroll
        for (int reg = 0; reg < 4; ++reg) {
            int t = tb + reg;
            if (t < TT - 1) pred[b * (TT - 1) + t] = fast_sigmoid(ps[reg] + pbv);
        }
    }
}

__global__ __launch_bounds__(256, 1) void fused_kernel(
    const float* __restrict__ W, const unsigned* __restrict__ EA,
    const float* __restrict__ Mv0, const unsigned short* __restrict__ Ko,
    const unsigned short* __restrict__ fWat, const float* __restrict__ pW,
    const float* __restrict__ pb,
    float* __restrict__ pred, float* __restrict__ MvWS,
    int t0, int Tc, int doInit, int doSave)
{
    const int b = blockIdx.x;
    const int tid = threadIdx.x;
    const int nch = Tc / CH;

    __shared__ __align__(16) float Wl[2][CH * WROW];            //  9.2 KB
    __shared__ __align__(16) unsigned short rtl[2][CH * RSTR];  // 17.4 KB
    __shared__ __align__(16) unsigned short fWl[128 * RSTR];    // 34.8 KB

    // stage fWat -> fWl (all 256 threads)
    {
        int n = tid >> 1, k0 = (tid & 1) * 64;
#pragma unroll
        for (int j = 0; j < 8; ++j)
            *(s16x8*)&fWl[n * RSTR + k0 + j * 8] = *(const s16x8*)&fWat[n * 128 + k0 + j * 8];
    }

    const int lr = tid >> 2, lq = tid & 3;
    const float* __restrict__ Wb = W + (size_t)b * Tc * 32;
    const uint4* __restrict__ EA4 = (const uint4*)EA;
    const int bq = b * nch;
    f32x2 Mv2[16];
    float4 wr0, wr1;
    float4 w0, w1, w2_, w3_, w4_, w5_, w6_, w7_;
    float4 u0, u1, u2, u3, u4, u5, u6, u7;
    uint4 erA[8], erB[8];
    float pbv = 0.f;

    if (tid < 128) {
        if (doInit) {
#pragma unroll
            for (int i = 0; i < 16; ++i)
                Mv2[i] = mk2(Mv0[(2 * i) * 128 + tid], Mv0[(2 * i + 1) * 128 + tid]);
        } else {
#pragma unroll
            for (int i = 0; i < 16; ++i)
                Mv2[i] = mk2(MvWS[(size_t)b * 4096 + (2 * i) * 128 + tid],
                             MvWS[(size_t)b * 4096 + (2 * i + 1) * 128 + tid]);
        }
        LOAD_W(0); PUB_W(0);
        LOAD_EA(erA, 0);
        if (nch > 1) LOAD_W(1);
    } else {
        pbv = pb[0];
    }
    __syncthreads();

    for (int g = 0; g < nch; g += 2) {
        // ---- even chunk g: produce -> slot0; consume chunk g-1 (slot1) ----
        if (tid < 128) {
            if (g + 1 < nch) PUB_W(g + 1);
            if (g + 2 < nch) LOAD_W(g + 2);
            if (g + 1 < nch) LOAD_EA(erB, g + 1);
            SEQ_CHUNK(erA, g, rtl[0]);
        } else if (g >= 1) {
            consume_chunk(g - 1, rtl[1], fWl, b, Tc, t0, Ko, pW, pbv, pred, tid);
        }
        __syncthreads();

        // ---- odd chunk g+1: produce -> slot1; consume chunk g (slot0) ----
        if (tid < 128) {
            if (g + 1 < nch) {
                if (g + 2 < nch) PUB_W(g + 2);
                if (g + 3 < nch) LOAD_W(g + 3);
                if (g + 2 < nch) LOAD_EA(erA, g + 2);
                SEQ_CHUNK(erB, g + 1, rtl[1]);
            }
        } else {
            consume_chunk(g, rtl[0], fWl, b, Tc, t0, Ko, pW, pbv, pred, tid);
        }
        __syncthreads();
    }
    // epilogue: for even nch the last (odd) chunk is still unconsumed
    if (!(nch & 1) && tid >= 128) {
        consume_chunk(nch - 1, rtl[1], fWl, b, Tc, t0, Ko, pW, pbv, pred, tid);
    }

    if (doSave && tid < 128) {
#pragma unroll
        for (int i = 0; i < 16; ++i) {
            MvWS[(size_t)b * 4096 + (2 * i) * 128 + tid]     = Mv2[i].x;
            MvWS[(size_t)b * 4096 + (2 * i + 1) * 128 + tid] = Mv2[i].y;
        }
    }
}

// ---------------------------------------------------------------------------

extern "C" void kernel_launch(void* const* d_in, const int* in_sizes, int n_in,
                              void* d_out, int out_size, void* d_ws, size_t ws_size,
                              hipStream_t stream) {
    const int*   skills    = (const int*)d_in[0];
    const int*   responses = (const int*)d_in[1];
    const float* k_emb     = (const float*)d_in[2];
    const float* v_emb     = (const float*)d_in[3];
    const float* Mk        = (const float*)d_in[4];
    const float* Mv0       = (const float*)d_in[5];
    const float* f_W       = (const float*)d_in[6];
    const float* f_b       = (const float*)d_in[7];
    const float* p_W       = (const float*)d_in[8];
    const float* p_b       = (const float*)d_in[9];
    const float* e_W       = (const float*)d_in[10];
    const float* e_b       = (const float*)d_in[11];
    const float* a_W       = (const float*)d_in[12];
    const float* a_b       = (const float*)d_in[13];

    float* pred    = (float*)d_out;                 // [256][255]
    float* outTrue = pred + BB * (TT - 1);          // [256][255]

    // scratch per row: Wo 128 B + EA 512 B + Ko 256 B = 896 B
    int Tc = TT;
    for (;;) {
        size_t need = (size_t)BB * Tc * 896 + 69632 * 2;
        if (Tc < TT) need += (size_t)BB * 4096 * 4;
        if (need <= ws_size || Tc <= 32) break;
        Tc >>= 1;
    }

    char* p = (char*)d_ws;
    float* Wo = (float*)p;                     p += (size_t)BB * Tc * 32 * 4;
    unsigned* EA = (unsigned*)p;               p += (size_t)BB * Tc * 128 * 4;
    unsigned short* Ko = (unsigned short*)p;   p += (size_t)BB * Tc * 128 * 2;
    unsigned short* eWt = (unsigned short*)p;  p += 16384 * 2;
    unsigned short* aWt = (unsigned short*)p;  p += 16384 * 2;
    unsigned short* fWat = (unsigned short*)p; p += 16384 * 2;
    unsigned short* fWbt = (unsigned short*)p; p += 16384 * 2;
    unsigned short* Mkt = (unsigned short*)p;  p += 4096 * 2;
    float* MvWS = (float*)p;

    conv_kernel<<<272, 256, 0, stream>>>(e_W, a_W, f_W, Mk,
                                         eWt, aWt, fWat, fWbt, Mkt);

    for (int t0 = 0; t0 < TT; t0 += Tc) {
        pre_kernel<<<(BB * Tc) / 64, 256, 0, stream>>>(
            skills, responses, k_emb, v_emb, f_b, e_b, a_b,
            Mkt, fWbt, eWt, aWt, Wo, EA, Ko, outTrue, t0, Tc);
        fused_kernel<<<BB, 256, 0, stream>>>(
            Wo, EA, Mv0, Ko, fWat, p_W, p_b, pred, MvWS,
            t0, Tc, t0 == 0 ? 1 : 0, (t0 + Tc < TT) ? 1 : 0);
    }
}

// Round 11
// 164.948 us; speedup vs baseline: 1.4301x; 1.0551x over previous
//
#include <hip/hip_runtime.h>
#include <math.h>

// Problem constants (fixed by setup_inputs)
#define BB 256      // batch
#define TT 256      // time steps
#define NQ 1000     // num_q
#define DK 128
#define DV 128
#define CC 32

typedef short s16x8 __attribute__((ext_vector_type(8)));   // 8 bf16 bit-patterns
typedef float f32x4 __attribute__((ext_vector_type(4)));
typedef float f32x2 __attribute__((ext_vector_type(2)));

__device__ __forceinline__ float fast_sigmoid(float x) {
    x = fminf(fmaxf(x, -30.f), 30.f);
    return 1.f / (1.f + __expf(-x));
}
__device__ __forceinline__ float fast_tanh(float x) {
    x = fminf(fmaxf(x, -15.f), 15.f);
    float t = __expf(2.f * x);
    return (t - 1.f) / (t + 1.f);
}
__device__ __forceinline__ unsigned short f2bf(float f) {   // RNE fp32->bf16
    unsigned u = __float_as_uint(f);
    u += 0x7fffu + ((u >> 16) & 1u);
    return (unsigned short)(u >> 16);
}
__device__ __forceinline__ float bf2f(unsigned short h) {
    return __uint_as_float((unsigned)h << 16);
}
__device__ __forceinline__ unsigned u4get(uint4 v, int i) { // i constant after unroll
    return i == 0 ? v.x : i == 1 ? v.y : i == 2 ? v.z : v.w;
}
__device__ __forceinline__ f32x2 mk2(float x, float y) { f32x2 r; r.x = x; r.y = y; return r; }
__device__ __forceinline__ f32x2 fma2(f32x2 a, f32x2 b, f32x2 c) {
    return __builtin_elementwise_fma(a, b, c);
}
__device__ __forceinline__ s16x8 cvt8(float4 v0, float4 v1) {
    s16x8 f;
    f[0] = (short)f2bf(v0.x); f[1] = (short)f2bf(v0.y);
    f[2] = (short)f2bf(v0.z); f[3] = (short)f2bf(v0.w);
    f[4] = (short)f2bf(v1.x); f[5] = (short)f2bf(v1.y);
    f[6] = (short)f2bf(v1.z); f[7] = (short)f2bf(v1.w);
    return f;
}

// ---------------------------------------------------------------------------
// conv_kernel: build bf16 TRANSPOSED weights in ws (B-operand layout Wt[n][k])
// ---------------------------------------------------------------------------
__global__ __launch_bounds__(256) void conv_kernel(
    const float* __restrict__ eW, const float* __restrict__ aW,
    const float* __restrict__ fW, const float* __restrict__ Mk,
    unsigned short* __restrict__ eWt, unsigned short* __restrict__ aWt,
    unsigned short* __restrict__ fWat, unsigned short* __restrict__ fWbt,
    unsigned short* __restrict__ Mkt)
{
    int idx = blockIdx.x * 256 + threadIdx.x;
    if (idx < 16384) {
        int n = idx >> 7, k = idx & 127;
        eWt[idx] = f2bf(eW[k * 128 + n]);
    } else if (idx < 32768) {
        int i = idx - 16384; int n = i >> 7, k = i & 127;
        aWt[i] = f2bf(aW[k * 128 + n]);
    } else if (idx < 49152) {
        int i = idx - 32768; int n = i >> 7, k = i & 127;
        fWat[i] = f2bf(fW[k * 128 + n]);
    } else if (idx < 65536) {
        int i = idx - 49152; int n = i >> 7, k = i & 127;
        fWbt[i] = f2bf(fW[(128 + k) * 128 + n]);
    } else if (idx < 69632) {
        int i = idx - 65536; int n = i >> 7, k = i & 127;   // n=c 0..31
        Mkt[i] = f2bf(Mk[k * 32 + n]);
    }
}

// ---------------------------------------------------------------------------
// pre_kernel v2 (R11): same math, data movement minimized.
//  * k/v gathered DIRECTLY into MFMA A-fragments (per-lane global loads +
//    f2bf) — Albs LDS round-trip removed.
//  * softmax IN-REGISTER via 16-lane shuffles — lg buffer removed.
//  * et parked in 32 registers between the e- and a-phases.
//  LDS: Wlds only (34.8 KB -> 4 blocks/CU resident vs 61 KB before);
//  barriers 9 -> 7.
// ---------------------------------------------------------------------------
__global__ __launch_bounds__(256) void pre_kernel(
    const int* __restrict__ skills, const int* __restrict__ responses,
    const float* __restrict__ k_emb, const float* __restrict__ v_emb,
    const float* __restrict__ fb, const float* __restrict__ eb,
    const float* __restrict__ ab,
    const unsigned short* __restrict__ Mkt, const unsigned short* __restrict__ fWbt,
    const unsigned short* __restrict__ eWt, const unsigned short* __restrict__ aWt,
    float* __restrict__ Wo, unsigned* __restrict__ EA,
    unsigned short* __restrict__ Ko, float* __restrict__ outTrue,
    int t0, int Tc)
{
    const int tid = threadIdx.x;
    const int lane = tid & 63;
    const int m_base = (tid >> 6) * 16;
    const int mrow = lane & 15, quad = lane >> 4;
    const size_t base = (size_t)blockIdx.x * 64;

    __shared__ __align__(16) unsigned short Wlds[128 * 136];   // 34.8 KB

    // per-lane gather row (A-side): row = base + m_base + mrow
    int grow = (int)base + m_base + mrow;
    int gb = grow / Tc;
    int gt = t0 + (grow - gb * Tc);
    int gi = gb * TT + gt;
    int s = skills[gi];
    int r = responses[gi];
    int q = s + NQ * ((r > -1) ? r : 0);
    if (quad == 0 && gt >= 1) outTrue[gb * (TT - 1) + (gt - 1)] = (float)r;

    // stage Mkt rows 0..31
    {
        int n = tid >> 3, k0 = (tid & 7) * 16;
        *(s16x8*)&Wlds[n * 136 + k0]     = *(const s16x8*)&Mkt[n * 128 + k0];
        *(s16x8*)&Wlds[n * 136 + k0 + 8] = *(const s16x8*)&Mkt[n * 128 + k0 + 8];
    }

    // gather kt A-frags direct to regs: aF[kb] = kt[row][kb*32 + quad*8 ..+7]
    s16x8 aF[4];
    {
        const float* kr = k_emb + (size_t)s * DK + quad * 8;
#pragma unroll
        for (int kb = 0; kb < 4; ++kb)
            aF[kb] = cvt8(*(const float4*)(kr + kb * 32),
                          *(const float4*)(kr + kb * 32 + 4));
    }
    __syncthreads();   // [1] Mkt staged

    // logits (NT=2) + in-register softmax -> Wo
    {
        f32x4 l0 = {0.f, 0.f, 0.f, 0.f}, l1 = {0.f, 0.f, 0.f, 0.f};
#pragma unroll
        for (int kb = 0; kb < 4; ++kb) {
            s16x8 b0 = *(const s16x8*)&Wlds[mrow * 136 + kb * 32 + quad * 8];
            s16x8 b1 = *(const s16x8*)&Wlds[(16 + mrow) * 136 + kb * 32 + quad * 8];
            l0 = __builtin_amdgcn_mfma_f32_16x16x32_bf16(aF[kb], b0, l0, 0, 0, 0);
            l1 = __builtin_amdgcn_mfma_f32_16x16x32_bf16(aF[kb], b1, l1, 0, 0, 0);
        }
        // lane holds cols {mrow, 16+mrow} for rows m_base + quad*4 + reg
#pragma unroll
        for (int reg = 0; reg < 4; ++reg) {
            float a0 = l0[reg], a1 = l1[reg];
            float m = fmaxf(a0, a1);
#pragma unroll
            for (int off = 1; off < 16; off <<= 1)
                m = fmaxf(m, __shfl_xor(m, off, 64));
            float e0 = __expf(a0 - m), e1 = __expf(a1 - m);
            float ssum = e0 + e1;
#pragma unroll
            for (int off = 1; off < 16; off <<= 1)
                ssum += __shfl_xor(ssum, off, 64);
            float inv = 1.f / ssum;
            size_t rowg = base + m_base + quad * 4 + reg;
            Wo[rowg * 32 + mrow]      = e0 * inv;
            Wo[rowg * 32 + 16 + mrow] = e1 * inv;
        }
    }
    __syncthreads();   // [2] logits' Wlds reads done

    // stage fWbt
    {
        int n = tid >> 1, k0 = (tid & 1) * 64;
#pragma unroll
        for (int j = 0; j < 8; ++j)
            *(s16x8*)&Wlds[n * 136 + k0 + j * 8] = *(const s16x8*)&fWbt[n * 128 + k0 + j * 8];
    }
    __syncthreads();   // [3]

    // gather vt frags early (global latency overlaps ck MFMA below)
    s16x8 vF[4];
    {
        const float* vr = v_emb + (size_t)q * DV + quad * 8;
#pragma unroll
        for (int kb = 0; kb < 4; ++kb)
            vF[kb] = cvt8(*(const float4*)(vr + kb * 32),
                          *(const float4*)(vr + kb * 32 + 4));
    }

    // ck = kt@fWb + fb -> Ko
#pragma unroll
    for (int nt = 0; nt < 8; ++nt) {
        f32x4 acc = {0.f, 0.f, 0.f, 0.f};
#pragma unroll
        for (int kb = 0; kb < 4; ++kb) {
            s16x8 bf = *(const s16x8*)&Wlds[(nt * 16 + mrow) * 136 + kb * 32 + quad * 8];
            acc = __builtin_amdgcn_mfma_f32_16x16x32_bf16(aF[kb], bf, acc, 0, 0, 0);
        }
        int col = nt * 16 + mrow;
        float fbv = fb[col];
#pragma unroll
        for (int reg = 0; reg < 4; ++reg) {
            size_t rr = base + m_base + quad * 4 + reg;
            Ko[rr * 128 + col] = f2bf(acc[reg] + fbv);
        }
    }
    __syncthreads();   // [4] ck's Wlds reads done

    // stage eWt
    {
        int n = tid >> 1, k0 = (tid & 1) * 64;
#pragma unroll
        for (int j = 0; j < 8; ++j)
            *(s16x8*)&Wlds[n * 136 + k0 + j * 8] = *(const s16x8*)&eWt[n * 128 + k0 + j * 8];
    }
    __syncthreads();   // [5]

    // et = sigmoid(vt@eW + eb) -> registers
    float etr[8][4];
#pragma unroll
    for (int nt = 0; nt < 8; ++nt) {
        f32x4 acc = {0.f, 0.f, 0.f, 0.f};
#pragma unroll
        for (int kb = 0; kb < 4; ++kb) {
            s16x8 bf = *(const s16x8*)&Wlds[(nt * 16 + mrow) * 136 + kb * 32 + quad * 8];
            acc = __builtin_amdgcn_mfma_f32_16x16x32_bf16(vF[kb], bf, acc, 0, 0, 0);
        }
        int col = nt * 16 + mrow;
        float ebv = eb[col];
#pragma unroll
        for (int reg = 0; reg < 4; ++reg)
            etr[nt][reg] = fast_sigmoid(acc[reg] + ebv);
    }
    __syncthreads();   // [6] et's Wlds reads done

    // stage aWt
    {
        int n = tid >> 1, k0 = (tid & 1) * 64;
#pragma unroll
        for (int j = 0; j < 8; ++j)
            *(s16x8*)&Wlds[n * 136 + k0 + j * 8] = *(const s16x8*)&aWt[n * 128 + k0 + j * 8];
    }
    __syncthreads();   // [7]

    // at = tanh(vt@aW + ab); pack (et,at) -> EA
#pragma unroll
    for (int nt = 0; nt < 8; ++nt) {
        f32x4 acc = {0.f, 0.f, 0.f, 0.f};
#pragma unroll
        for (int kb = 0; kb < 4; ++kb) {
            s16x8 bf = *(const s16x8*)&Wlds[(nt * 16 + mrow) * 136 + kb * 32 + quad * 8];
            acc = __builtin_amdgcn_mfma_f32_16x16x32_bf16(vF[kb], bf, acc, 0, 0, 0);
        }
        int col = nt * 16 + mrow;
        float abv = ab[col];
#pragma unroll
        for (int reg = 0; reg < 4; ++reg) {
            size_t rr = base + m_base + quad * 4 + reg;
            int bb = (int)(rr / (size_t)Tc);
            int t  = (int)(rr - (size_t)bb * Tc);
            size_t o4 = (((size_t)bb * (Tc >> 5) + (t >> 5)) * 8 + ((t >> 2) & 7)) * 128 + col;
            unsigned lo = f2bf(etr[nt][reg]);
            unsigned hi = (unsigned)f2bf(fast_tanh(acc[reg] + abv)) << 16;
            EA[o4 * 4 + (t & 3)] = hi | lo;
        }
    }
}

// ---------------------------------------------------------------------------
// fused_kernel v5 (seq + post) — R11:
//  R10 named-var pipeline + __builtin_amdgcn_sched_barrier(0) fences. R10's
//  VGPR=108 showed the SCHEDULER collapsed the pipeline (sank PREF next to
//  STEP to shrink live ranges) even though SROA succeeded. The fences pin:
//  issue next step's 8 ds_reads, THEN current step's ~160 cyc of packed FMA
//  -> ~120 cyc LDS latency covered. RSTR=136 (R9 A/B: padding hurt).
// ---------------------------------------------------------------------------

#define CH 32
#define WROW 36     // Wl row stride (floats)
#define RSTR 136    // rtl/fWl row stride (shorts)
#define SB() __builtin_amdgcn_sched_barrier(0)

#define LOAD_W(gg) do {                                                       \
    const float* ws = Wb + (size_t)(gg) * CH * 32;                            \
    wr0 = *(const float4*)(ws + tid * 8);                                     \
    wr1 = *(const float4*)(ws + tid * 8 + 4);                                 \
} while (0)

#define PUB_W(gg) do {                                                        \
    float* wd = &Wl[(gg) & 1][lr * WROW + lq * 8];                            \
    *(float4*)wd = wr0; *(float4*)(wd + 4) = wr1;                             \
} while (0)

#define LOAD_EA(ER, gg) do {                                                  \
    const uint4* src = EA4 + ((size_t)(bq + (gg))) * 1024 + tid;              \
    _Pragma("unroll")                                                         \
    for (int j = 0; j < 8; ++j) ER[j] = src[j * 128];                         \
} while (0)

// prefetch w row `rowidx` (compile-time after unroll) into 8 named float4s
#define PREF8(A0,A1,A2,A3,A4,A5,A6,A7, rowidx) do {                           \
    const float* _wr = wlc + (rowidx) * WROW;                                 \
    A0 = *(const float4*)(_wr + 0);  A1 = *(const float4*)(_wr + 4);          \
    A2 = *(const float4*)(_wr + 8);  A3 = *(const float4*)(_wr + 12);         \
    A4 = *(const float4*)(_wr + 16); A5 = *(const float4*)(_wr + 20);         \
    A6 = *(const float4*)(_wr + 24); A7 = *(const float4*)(_wr + 28);         \
} while (0)

// one chain step from 8 named register-resident float4s
#define STEP8(A0,A1,A2,A3,A4,A5,A6,A7, ER, tl) do {                           \
    f32x2 w2[16];                                                             \
    w2[0]  = mk2(A0.x, A0.y); w2[1]  = mk2(A0.z, A0.w);                       \
    w2[2]  = mk2(A1.x, A1.y); w2[3]  = mk2(A1.z, A1.w);                       \
    w2[4]  = mk2(A2.x, A2.y); w2[5]  = mk2(A2.z, A2.w);                       \
    w2[6]  = mk2(A3.x, A3.y); w2[7]  = mk2(A3.z, A3.w);                       \
    w2[8]  = mk2(A4.x, A4.y); w2[9]  = mk2(A4.z, A4.w);                       \
    w2[10] = mk2(A5.x, A5.y); w2[11] = mk2(A5.z, A5.w);                       \
    w2[12] = mk2(A6.x, A6.y); w2[13] = mk2(A6.z, A6.w);                       \
    w2[14] = mk2(A7.x, A7.y); w2[15] = mk2(A7.z, A7.w);                       \
    unsigned ea = u4get(ER[(tl) >> 2], (tl) & 3);                             \
    float e = __uint_as_float(ea << 16);                                      \
    float a = __uint_as_float(ea & 0xffff0000u);                              \
    f32x2 ne2 = mk2(-e, -e);                                                  \
    f32x2 a2  = mk2(a, a);                                                    \
    f32x2 r0 = mk2(0.f, 0.f), r1 = r0, r2 = r0, r3 = r0;                      \
    _Pragma("unroll")                                                         \
    for (int q = 0; q < 4; ++q) {                                             \
        r0 = fma2(w2[4*q+0], Mv2[4*q+0], r0);                                 \
        r1 = fma2(w2[4*q+1], Mv2[4*q+1], r1);                                 \
        r2 = fma2(w2[4*q+2], Mv2[4*q+2], r2);                                 \
        r3 = fma2(w2[4*q+3], Mv2[4*q+3], r3);                                 \
    }                                                                         \
    f32x2 rs = (r0 + r1) + (r2 + r3);                                         \
    slp[(tl) * RSTR + tid] = f2bf(rs.x + rs.y);                               \
    _Pragma("unroll")                                                         \
    for (int i = 0; i < 16; ++i)                                              \
        Mv2[i] = fma2(w2[i], fma2(ne2, Mv2[i], a2), Mv2[i]);                  \
} while (0)

// chunk with sched_barrier-pinned 1-step-ahead w pipeline
#define SEQ_CHUNK(ER, gg, SL) do {                                            \
    const float* wlc = Wl[(gg) & 1];                                          \
    unsigned short* slp = SL;                                                 \
    PREF8(w0,w1,w2_,w3_,w4_,w5_,w6_,w7_, 0);                                  \
    _Pragma("unroll")                                                         \
    for (int tp = 0; tp < 16; ++tp) {                                         \
        SB(); PREF8(u0,u1,u2,u3,u4,u5,u6,u7, 2 * tp + 1); SB();               \
        STEP8(w0,w1,w2_,w3_,w4_,w5_,w6_,w7_, ER, 2 * tp);                     \
        SB(); PREF8(w0,w1,w2_,w3_,w4_,w5_,w6_,w7_,                            \
                    (2 * tp + 2 < 32) ? (2 * tp + 2) : 31); SB();             \
        STEP8(u0,u1,u2,u3,u4,u5,u6,u7, ER, 2 * tp + 1);                       \
    }                                                                         \
} while (0)

__device__ __forceinline__ void consume_chunk(
    int gc, const unsigned short* sl, const unsigned short* fWl,
    int b, int Tc, int t0,
    const unsigned short* __restrict__ Ko, const float* __restrict__ pW,
    float pbv, float* __restrict__ pred, int tid)
{
    const int lane = tid & 63;
    const int cw = (tid >> 6) & 1;          // consumer wave 0/1 -> rows cw*16..+15
    const int mrow = lane & 15, quad = lane >> 4;
    s16x8 aF[4];
#pragma unroll
    for (int kb = 0; kb < 4; ++kb)
        aF[kb] = *(const s16x8*)&sl[(cw * 16 + mrow) * RSTR + kb * 32 + quad * 8];
    float p0 = 0.f, p1 = 0.f, p2 = 0.f, p3 = 0.f;
    size_t rbase = (size_t)b * Tc + gc * CH + cw * 16 + quad * 4;
#pragma unroll
    for (int nt = 0; nt < 8; ++nt) {
        f32x4 acc = {0.f, 0.f, 0.f, 0.f};
#pragma unroll
        for (int kb = 0; kb < 4; ++kb) {
            s16x8 bf = *(const s16x8*)&fWl[(nt * 16 + mrow) * RSTR + kb * 32 + quad * 8];
            acc = __builtin_amdgcn_mfma_f32_16x16x32_bf16(aF[kb], bf, acc, 0, 0, 0);
        }
        int col = nt * 16 + mrow;
        float pw = pW[col];
        p0 = fmaf(fast_tanh(acc[0] + bf2f(Ko[(rbase + 0) * 128 + col])), pw, p0);
        p1 = fmaf(fast_tanh(acc[1] + bf2f(Ko[(rbase + 1) * 128 + col])), pw, p1);
        p2 = fmaf(fast_tanh(acc[2] + bf2f(Ko[(rbase + 2) * 128 + col])), pw, p2);
        p3 = fmaf(fast_tanh(acc[3] + bf2f(Ko[(rbase + 3) * 128 + col])), pw, p3);
    }
#pragma unroll
    for (int off = 1; off < 16; off <<= 1) {
        p0 += __shfl_xor(p0, off, 64); p1 += __shfl_xor(p1, off, 64);
        p2 += __shfl_xor(p2, off, 64); p3 += __shfl_xor(p3, off, 64);
    }
    if (mrow == 0) {
        int tb = t0 + gc * CH + cw * 16 + quad * 4;
        float ps[4] = {p0, p1, p2, p3};
#pragma unroll
        for (int reg = 0; reg < 4; ++reg) {
            int t = tb + reg;
            if (t < TT - 1) pred[b * (TT - 1) + t] = fast_sigmoid(ps[reg] + pbv);
        }
    }
}

__global__ __launch_bounds__(256, 1) void fused_kernel(
    const float* __restrict__ W, const unsigned* __restrict__ EA,
    const float* __restrict__ Mv0, const unsigned short* __restrict__ Ko,
    const unsigned short* __restrict__ fWat, const float* __restrict__ pW,
    const float* __restrict__ pb,
    float* __restrict__ pred, float* __restrict__ MvWS,
    int t0, int Tc, int doInit, int doSave)
{
    const int b = blockIdx.x;
    const int tid = threadIdx.x;
    const int nch = Tc / CH;

    __shared__ __align__(16) float Wl[2][CH * WROW];            //  9.2 KB
    __shared__ __align__(16) unsigned short rtl[2][CH * RSTR];  // 17.4 KB
    __shared__ __align__(16) unsigned short fWl[128 * RSTR];    // 34.8 KB

    // stage fWat -> fWl (all 256 threads)
    {
        int n = tid >> 1, k0 = (tid & 1) * 64;
#pragma unroll
        for (int j = 0; j < 8; ++j)
            *(s16x8*)&fWl[n * RSTR + k0 + j * 8] = *(const s16x8*)&fWat[n * 128 + k0 + j * 8];
    }

    const int lr = tid >> 2, lq = tid & 3;
    const float* __restrict__ Wb = W + (size_t)b * Tc * 32;
    const uint4* __restrict__ EA4 = (const uint4*)EA;
    const int bq = b * nch;
    f32x2 Mv2[16];
    float4 wr0, wr1;
    float4 w0, w1, w2_, w3_, w4_, w5_, w6_, w7_;
    float4 u0, u1, u2, u3, u4, u5, u6, u7;
    uint4 erA[8], erB[8];
    float pbv = 0.f;

    if (tid < 128) {
        if (doInit) {
#pragma unroll
            for (int i = 0; i < 16; ++i)
                Mv2[i] = mk2(Mv0[(2 * i) * 128 + tid], Mv0[(2 * i + 1) * 128 + tid]);
        } else {
#pragma unroll
            for (int i = 0; i < 16; ++i)
                Mv2[i] = mk2(MvWS[(size_t)b * 4096 + (2 * i) * 128 + tid],
                             MvWS[(size_t)b * 4096 + (2 * i + 1) * 128 + tid]);
        }
        LOAD_W(0); PUB_W(0);
        LOAD_EA(erA, 0);
        if (nch > 1) LOAD_W(1);
    } else {
        pbv = pb[0];
    }
    __syncthreads();

    for (int g = 0; g < nch; g += 2) {
        // ---- even chunk g: produce -> slot0; consume chunk g-1 (slot1) ----
        if (tid < 128) {
            if (g + 1 < nch) PUB_W(g + 1);
            if (g + 2 < nch) LOAD_W(g + 2);
            if (g + 1 < nch) LOAD_EA(erB, g + 1);
            SEQ_CHUNK(erA, g, rtl[0]);
        } else if (g >= 1) {
            consume_chunk(g - 1, rtl[1], fWl, b, Tc, t0, Ko, pW, pbv, pred, tid);
        }
        __syncthreads();

        // ---- odd chunk g+1: produce -> slot1; consume chunk g (slot0) ----
        if (tid < 128) {
            if (g + 1 < nch) {
                if (g + 2 < nch) PUB_W(g + 2);
                if (g + 3 < nch) LOAD_W(g + 3);
                if (g + 2 < nch) LOAD_EA(erA, g + 2);
                SEQ_CHUNK(erB, g + 1, rtl[1]);
            }
        } else {
            consume_chunk(g, rtl[0], fWl, b, Tc, t0, Ko, pW, pbv, pred, tid);
        }
        __syncthreads();
    }
    // epilogue: for even nch the last (odd) chunk is still unconsumed
    if (!(nch & 1) && tid >= 128) {
        consume_chunk(nch - 1, rtl[1], fWl, b, Tc, t0, Ko, pW, pbv, pred, tid);
    }

    if (doSave && tid < 128) {
#pragma unroll
        for (int i = 0; i < 16; ++i) {
            MvWS[(size_t)b * 4096 + (2 * i) * 128 + tid]     = Mv2[i].x;
            MvWS[(size_t)b * 4096 + (2 * i + 1) * 128 + tid] = Mv2[i].y;
        }
    }
}

// ---------------------------------------------------------------------------

extern "C" void kernel_launch(void* const* d_in, const int* in_sizes, int n_in,
                              void* d_out, int out_size, void* d_ws, size_t ws_size,
                              hipStream_t stream) {
    const int*   skills    = (const int*)d_in[0];
    const int*   responses = (const int*)d_in[1];
    const float* k_emb     = (const float*)d_in[2];
    const float* v_emb     = (const float*)d_in[3];
    const float* Mk        = (const float*)d_in[4];
    const float* Mv0       = (const float*)d_in[5];
    const float* f_W       = (const float*)d_in[6];
    const float* f_b       = (const float*)d_in[7];
    const float* p_W       = (const float*)d_in[8];
    const float* p_b       = (const float*)d_in[9];
    const float* e_W       = (const float*)d_in[10];
    const float* e_b       = (const float*)d_in[11];
    const float* a_W       = (const float*)d_in[12];
    const float* a_b       = (const float*)d_in[13];

    float* pred    = (float*)d_out;                 // [256][255]
    float* outTrue = pred + BB * (TT - 1);          // [256][255]

    // scratch per row: Wo 128 B + EA 512 B + Ko 256 B = 896 B
    int Tc = TT;
    for (;;) {
        size_t need = (size_t)BB * Tc * 896 + 69632 * 2;
        if (Tc < TT) need += (size_t)BB * 4096 * 4;
        if (need <= ws_size || Tc <= 32) break;
        Tc >>= 1;
    }

    char* p = (char*)d_ws;
    float* Wo = (float*)p;                     p += (size_t)BB * Tc * 32 * 4;
    unsigned* EA = (unsigned*)p;               p += (size_t)BB * Tc * 128 * 4;
    unsigned short* Ko = (unsigned short*)p;   p += (size_t)BB * Tc * 128 * 2;
    unsigned short* eWt = (unsigned short*)p;  p += 16384 * 2;
    unsigned short* aWt = (unsigned short*)p;  p += 16384 * 2;
    unsigned short* fWat = (unsigned short*)p; p += 16384 * 2;
    unsigned short* fWbt = (unsigned short*)p; p += 16384 * 2;
    unsigned short* Mkt = (unsigned short*)p;  p += 4096 * 2;
    float* MvWS = (float*)p;

    conv_kernel<<<272, 256, 0, stream>>>(e_W, a_W, f_W, Mk,
                                         eWt, aWt, fWat, fWbt, Mkt);

    for (int t0 = 0; t0 < TT; t0 += Tc) {
        pre_kernel<<<(BB * Tc) / 64, 256, 0, stream>>>(
            skills, responses, k_emb, v_emb, f_b, e_b, a_b,
            Mkt, fWbt, eWt, aWt, Wo, EA, Ko, outTrue, t0, Tc);
        fused_kernel<<<BB, 256, 0, stream>>>(
            Wo, EA, Mv0, Ko, fWat, p_W, p_b, pred, MvWS,
            t0, Tc, t0 == 0 ? 1 : 0, (t0 + Tc < TT) ? 1 : 0);
    }
}